// Round 2
// baseline (6748.259 us; speedup 1.0000x reference)
//
#include <hip/hip_runtime.h>
#include <hip/hip_bf16.h>

#define B_ 8
#define T_ 2048
#define C_ 768
#define H_ 3072
#define BT_ (B_ * T_)
#define CHUNK_ 2048

typedef __hip_bfloat16 bf16;

// ---------------------------------------------------------------- LayerNorm
__global__ void ln_kernel(const float* __restrict__ x, const float* __restrict__ w,
                          const float* __restrict__ b, float* __restrict__ out) {
    int row = blockIdx.x;
    const float* xr = x + (size_t)row * C_;
    float* orow = out + (size_t)row * C_;
    int tid = threadIdx.x;
    float s = 0.f, s2 = 0.f;
    for (int i = tid; i < C_; i += 256) { float v = xr[i]; s += v; s2 += v * v; }
    for (int off = 32; off > 0; off >>= 1) {
        s += __shfl_down(s, off);
        s2 += __shfl_down(s2, off);
    }
    __shared__ float ls[4], ls2[4];
    int wid = tid >> 6, lane = tid & 63;
    if (lane == 0) { ls[wid] = s; ls2[wid] = s2; }
    __syncthreads();
    if (tid == 0) {
        float a = 0.f, a2 = 0.f;
        for (int i = 0; i < 4; ++i) { a += ls[i]; a2 += ls2[i]; }
        ls[0] = a; ls2[0] = a2;
    }
    __syncthreads();
    float mu = ls[0] * (1.f / C_);
    float var = ls2[0] * (1.f / C_) - mu * mu;
    float rs = rsqrtf(var + 1e-5f);
    for (int i = tid; i < C_; i += 256) {
        orow[i] = (xr[i] - mu) * rs * w[i] + b[i];
    }
}

// ---------------------------------------------------------------- fused GEMM
// C[M,N] = f( mix(A)[M,K] @ W[K,N] )
// MIX: A-element (row,c) = A[row,c]*mix[c] + A[row-1,c]*(1-mix[c]), 0-padded at t==0
//      (t = (row_off + row) % T_)
// MODE: 0=none, 1=sigmoid, 2=relu^2.  OutT: float or bf16.
__device__ inline float4 blend4(float4 cur, float4 prev, float4 m) {
    float4 o;
    o.x = fmaf(m.x, cur.x - prev.x, prev.x);
    o.y = fmaf(m.y, cur.y - prev.y, prev.y);
    o.z = fmaf(m.z, cur.z - prev.z, prev.z);
    o.w = fmaf(m.w, cur.w - prev.w, prev.w);
    return o;
}

template<int MODE, bool MIX, typename OutT>
__global__ __launch_bounds__(256)
void gemm_t(const float* __restrict__ A, const float* __restrict__ mixv,
            const float* __restrict__ W, OutT* __restrict__ Cm,
            int N, int K, int row_off) {
    __shared__ float As[16][132];
    __shared__ float Ws[16][136];
    const int tid = threadIdx.x;
    const int tx = tid & 15;
    const int ty = tid >> 4;
    const int m0 = blockIdx.y << 7;
    const int n0 = blockIdx.x << 7;

    const int arow = tid >> 1;         // 0..127
    const int acol = (tid & 1) << 3;   // 0 or 8
    const int wrow = tid >> 4;         // 0..15
    const int wcol = (tid & 15) << 3;  // 0..120

    const int grow = m0 + arow;
    const int t = (row_off + grow) % T_;

    const float* Ap = A + (size_t)grow * K + acol;
    const float* Wp = W + (size_t)wrow * N + (n0 + wcol);

    float acc[8][8];
#pragma unroll
    for (int i = 0; i < 8; ++i)
#pragma unroll
        for (int j = 0; j < 8; ++j) acc[i][j] = 0.f;

    const int nk = K >> 4;
    for (int kt = 0; kt < nk; ++kt) {
        float4 a0 = *(const float4*)Ap;
        float4 a1 = *(const float4*)(Ap + 4);
        if constexpr (MIX) {
            float4 p0 = make_float4(0.f, 0.f, 0.f, 0.f);
            float4 p1 = make_float4(0.f, 0.f, 0.f, 0.f);
            if (t > 0) {
                p0 = *(const float4*)(Ap - K);
                p1 = *(const float4*)(Ap - K + 4);
            }
            const float* mvp = mixv + (kt << 4) + acol;
            float4 mA = *(const float4*)mvp;
            float4 mB = *(const float4*)(mvp + 4);
            a0 = blend4(a0, p0, mA);
            a1 = blend4(a1, p1, mB);
        }
        float4 w0 = *(const float4*)Wp;
        float4 w1 = *(const float4*)(Wp + 4);
        __syncthreads();
        As[acol + 0][arow] = a0.x; As[acol + 1][arow] = a0.y;
        As[acol + 2][arow] = a0.z; As[acol + 3][arow] = a0.w;
        As[acol + 4][arow] = a1.x; As[acol + 5][arow] = a1.y;
        As[acol + 6][arow] = a1.z; As[acol + 7][arow] = a1.w;
        *(float4*)&Ws[wrow][wcol] = w0;
        *(float4*)&Ws[wrow][wcol + 4] = w1;
        __syncthreads();
        Ap += 16;
        Wp += (size_t)16 * N;
#pragma unroll
        for (int kk = 0; kk < 16; ++kk) {
            float4 ra0 = *(const float4*)&As[kk][ty << 2];
            float4 ra1 = *(const float4*)&As[kk][(ty << 2) + 64];
            float4 rb0 = *(const float4*)&Ws[kk][tx << 2];
            float4 rb1 = *(const float4*)&Ws[kk][(tx << 2) + 64];
            float av[8] = {ra0.x, ra0.y, ra0.z, ra0.w, ra1.x, ra1.y, ra1.z, ra1.w};
            float bv[8] = {rb0.x, rb0.y, rb0.z, rb0.w, rb1.x, rb1.y, rb1.z, rb1.w};
#pragma unroll
            for (int i = 0; i < 8; ++i)
#pragma unroll
                for (int j = 0; j < 8; ++j) acc[i][j] += av[i] * bv[j];
        }
    }

#pragma unroll
    for (int i = 0; i < 8; ++i) {
        int row = m0 + ((i < 4) ? (ty * 4 + i) : (64 + ty * 4 + (i - 4)));
        float ov[8];
#pragma unroll
        for (int j = 0; j < 8; ++j) {
            float v = acc[i][j];
            if constexpr (MODE == 1) v = 1.f / (1.f + expf(-v));
            if constexpr (MODE == 2) { v = fmaxf(v, 0.f); v = v * v; }
            ov[j] = v;
        }
        size_t base = (size_t)row * N + n0 + tx * 4;
        if constexpr (sizeof(OutT) == 2) {
            union { bf16 h[4]; ushort4 u; } lo, hi;
#pragma unroll
            for (int j = 0; j < 4; ++j) {
                lo.h[j] = __float2bfloat16(ov[j]);
                hi.h[j] = __float2bfloat16(ov[j + 4]);
            }
            *reinterpret_cast<ushort4*>((bf16*)Cm + base) = lo.u;
            *reinterpret_cast<ushort4*>((bf16*)Cm + base + 64) = hi.u;
        } else {
            *(float4*)((float*)Cm + base) = make_float4(ov[0], ov[1], ov[2], ov[3]);
            *(float4*)((float*)Cm + base + 64) = make_float4(ov[4], ov[5], ov[6], ov[7]);
        }
    }
}

// ---------------------------------------------------------------- WKV scan (bf16 k,v)
__global__ void wkv_kernel(const float* __restrict__ td, const float* __restrict__ tf,
                           const bf16* __restrict__ K, const bf16* __restrict__ V,
                           float* __restrict__ Y) {
    int idx = blockIdx.x * 256 + threadIdx.x;  // < B_*C_
    int b = idx / C_;
    int c = idx - b * C_;
    float w = -expf(td[c]);
    float u = tf[c];
    size_t off = (size_t)b * T_ * C_ + c;
    const bf16* kp = K + off;
    const bf16* vp = V + off;
    float* yp = Y + off;
    float aa = 0.f, bb = 0.f, pp = -1e38f;
    for (int t = 0; t < T_; ++t) {
        float kt = __bfloat162float(kp[(size_t)t * C_]);
        float vt = __bfloat162float(vp[(size_t)t * C_]);
        float ww = u + kt;
        float p = fmaxf(pp, ww);
        float e1 = expf(pp - p);
        float e2 = expf(ww - p);
        yp[(size_t)t * C_] = (e1 * aa + e2 * vt) / (e1 * bb + e2);
        float ww2 = pp + w;
        float p2 = fmaxf(ww2, kt);
        float e1b = expf(ww2 - p2);
        float e2b = expf(kt - p2);
        aa = e1b * aa + e2b * vt;
        bb = e1b * bb + e2b;
        pp = p2;
    }
}

// ---------------------------------------------------------------- elementwise mul
__global__ void mul_kernel(const float* __restrict__ a, const float* __restrict__ b,
                           float* __restrict__ o) {
    int i = blockIdx.x * blockDim.x + threadIdx.x;  // element/4, exact grid
    float4 av = ((const float4*)a)[i];
    float4 bv = ((const float4*)b)[i];
    float4 ov;
    ov.x = av.x * bv.x; ov.y = av.y * bv.y; ov.z = av.z * bv.z; ov.w = av.w * bv.w;
    ((float4*)o)[i] = ov;
}

// ---------------------------------------------------------------- LIF + residual
__global__ void lif_add_kernel(const float* __restrict__ cur, const float* __restrict__ base,
                               float* __restrict__ out) {
    int idx = blockIdx.x * 256 + threadIdx.x;  // < B_*C_
    int b = idx / C_;
    int c = idx - b * C_;
    size_t off = (size_t)b * T_ * C_ + c;
    const float* cp = cur + off;
    const float* bp = base + off;
    float* op = out + off;
    float v = 0.f;
    for (int t = 0; t < T_; ++t) {
        float xt = cp[(size_t)t * C_];
        v = v + (xt - v) * 0.5f;
        float s = (v >= 1.0f) ? 1.f : 0.f;
        op[(size_t)t * C_] = bp[(size_t)t * C_] + s;
        if (s > 0.f) v = 0.f;
    }
}

// ---------------------------------------------------------------- launcher
extern "C" void kernel_launch(void* const* d_in, const int* in_sizes, int n_in,
                              void* d_out, int out_size, void* d_ws, size_t ws_size,
                              hipStream_t stream) {
    const float* x    = (const float*)d_in[0];
    const float* ln1w = (const float*)d_in[1];
    const float* ln1b = (const float*)d_in[2];
    const float* ln2w = (const float*)d_in[3];
    const float* ln2b = (const float*)d_in[4];
    const float* td   = (const float*)d_in[5];
    const float* tf   = (const float*)d_in[6];
    const float* amk  = (const float*)d_in[7];
    const float* amv  = (const float*)d_in[8];
    const float* amr  = (const float*)d_in[9];
    const float* aWk  = (const float*)d_in[10];
    const float* aWv  = (const float*)d_in[11];
    const float* aWr  = (const float*)d_in[12];
    const float* aWo  = (const float*)d_in[13];
    const float* fmk  = (const float*)d_in[14];
    const float* fmr  = (const float*)d_in[15];
    const float* fWk  = (const float*)d_in[16];
    const float* fWv  = (const float*)d_in[17];
    const float* fWr  = (const float*)d_in[18];
    float* out = (float*)d_out;

    const size_t NBC = (size_t)BT_ * C_;
    float* bufA = (float*)d_ws;                       // NBC
    float* bufB = bufA + NBC;                         // NBC
    float* bufH = bufB + NBC;                         // CHUNK_*H_
    float* bufKV = bufH + (size_t)CHUNK_ * H_;        // CHUNK_*C_
    // total ws: (2*NBC + CHUNK_*H_ + CHUNK_*C_)*4 = 132.1 MB

    bf16* Kbf = (bf16*)bufB;
    bf16* Vbf = Kbf + NBC;
    float* Rs = out;  // d_out as scratch until X2 lands there

    const int ew_grid = (int)(NBC / 4 / 256);          // 12288
    const int ew_chunk = (int)((size_t)CHUNK_ * C_ / 4 / 256);  // 1536
    dim3 gP(C_ / 128, BT_ / 128);                      // (6,128)

    // 1. L = ln1(x) -> bufA
    ln_kernel<<<BT_, 256, 0, stream>>>(x, ln1w, ln1b, bufA);
    // 2-4. K,V (bf16), sigmoid(R) projections with fused token-shift mix
    gemm_t<0, true, bf16><<<gP, 256, 0, stream>>>(bufA, amk, aWk, Kbf, C_, C_, 0);
    gemm_t<0, true, bf16><<<gP, 256, 0, stream>>>(bufA, amv, aWv, Vbf, C_, C_, 0);
    gemm_t<1, true, float><<<gP, 256, 0, stream>>>(bufA, amr, aWr, Rs, C_, C_, 0);
    // 5. Y = wkv(K,V) -> bufA (L dead)
    wkv_kernel<<<(B_ * C_) / 256, 256, 0, stream>>>(td, tf, Kbf, Vbf, bufA);
    // 6. RY = Rs * Y -> bufB (K,V dead)
    mul_kernel<<<ew_grid, 256, 0, stream>>>(Rs, bufA, bufB);
    // 7. A_out = RY @ Wo -> bufA (Y dead)
    gemm_t<0, false, float><<<gP, 256, 0, stream>>>(bufB, nullptr, aWo, bufA, C_, C_, 0);
    // 8. X2 = x + lif(A_out) -> d_out (Rs dead)
    lif_add_kernel<<<(B_ * C_) / 256, 256, 0, stream>>>(bufA, x, out);
    // 9. L2 = ln2(X2) -> bufB (RY dead)
    ln_kernel<<<BT_, 256, 0, stream>>>(out, ln2w, ln2b, bufB);
    // 10. RRs = sigmoid(mix_r(L2) @ Wr) -> bufA (A_out dead)
    gemm_t<1, true, float><<<gP, 256, 0, stream>>>(bufB, fmr, fWr, bufA, C_, C_, 0);
    // 11. FFN per batch-chunk: H = relu^2(mix_k(L2)@Wk); KV = H@Wv; F = RRs*KV (in place)
    for (int ch = 0; ch < BT_ / CHUNK_; ++ch) {
        const float* l2p = bufB + (size_t)ch * CHUNK_ * C_;
        float* fp = bufA + (size_t)ch * CHUNK_ * C_;
        dim3 g1(H_ / 128, CHUNK_ / 128);
        gemm_t<2, true, float><<<g1, 256, 0, stream>>>(l2p, fmk, fWk, bufH, H_, C_, ch * CHUNK_);
        dim3 g2(C_ / 128, CHUNK_ / 128);
        gemm_t<0, false, float><<<g2, 256, 0, stream>>>(bufH, nullptr, fWv, bufKV, C_, H_, 0);
        mul_kernel<<<ew_chunk, 256, 0, stream>>>(fp, bufKV, fp);
    }
    // 12. out = X2 + lif(F)   (base==out aliasing is safe: per-element read-then-write)
    lif_add_kernel<<<(B_ * C_) / 256, 256, 0, stream>>>(bufA, out, out);
}

// Round 3
// 1166.581 us; speedup vs baseline: 5.7846x; 5.7846x over previous
//
#include <hip/hip_runtime.h>

#define B_ 8
#define T_ 2048
#define C_ 768
#define H_ 3072
#define BT_ (B_ * T_)
#define BC_ (B_ * C_)
#define WSEG 128
#define NWSEG 16
#define LSEG 256
#define NLSEG 8
#define LWARM 96

typedef unsigned short u16;
typedef short bf16x8 __attribute__((ext_vector_type(8)));
typedef float f32x4 __attribute__((ext_vector_type(4)));

__device__ inline float b2f(u16 u) {
    union { unsigned i; float f; } w; w.i = ((unsigned)u) << 16; return w.f;
}
__device__ inline u16 f2b(float f) {
    union { float f; unsigned i; } w; w.f = f;
    return (u16)((w.i + 0x7fffu + ((w.i >> 16) & 1u)) >> 16);
}

// ---------------------------------------------------------------- LayerNorm (f32 in, bf16 out)
__global__ void ln_kernel(const float* __restrict__ x, const float* __restrict__ w,
                          const float* __restrict__ b, u16* __restrict__ out) {
    int row = blockIdx.x;
    const float* xr = x + (size_t)row * C_;
    u16* orow = out + (size_t)row * C_;
    int tid = threadIdx.x;
    float s = 0.f, s2 = 0.f;
    for (int i = tid; i < C_; i += 256) { float v = xr[i]; s += v; s2 += v * v; }
    for (int off = 32; off > 0; off >>= 1) {
        s += __shfl_down(s, off);
        s2 += __shfl_down(s2, off);
    }
    __shared__ float ls[4], ls2[4];
    int wid = tid >> 6, lane = tid & 63;
    if (lane == 0) { ls[wid] = s; ls2[wid] = s2; }
    __syncthreads();
    if (tid == 0) {
        float a = 0.f, a2 = 0.f;
        for (int i = 0; i < 4; ++i) { a += ls[i]; a2 += ls2[i]; }
        ls[0] = a; ls2[0] = a2;
    }
    __syncthreads();
    float mu = ls[0] * (1.f / C_);
    float var = ls2[0] * (1.f / C_) - mu * mu;
    float rs = rsqrtf(var + 1e-5f);
    for (int i = tid; i < C_; i += 256) {
        orow[i] = f2b((xr[i] - mu) * rs * w[i] + b[i]);
    }
}

// ---------------------------------------------------------------- transpose-cast f32[R][N] -> bf16[N][R]
__global__ void tcast(const float* __restrict__ src, u16* __restrict__ dst, int R, int Ncol) {
    __shared__ float t[32][33];
    int c0 = blockIdx.x * 32, r0 = blockIdx.y * 32;
    int col = threadIdx.x & 31, rw = threadIdx.x >> 5;
#pragma unroll
    for (int i = 0; i < 4; ++i) {
        int r = rw + i * 8;
        t[r][col] = src[(size_t)(r0 + r) * Ncol + c0 + col];
    }
    __syncthreads();
#pragma unroll
    for (int i = 0; i < 4; ++i) {
        int r = rw + i * 8;
        dst[(size_t)(c0 + r) * R + r0 + col] = f2b(t[col][r]);
    }
}

// ---------------------------------------------------------------- bf16 MFMA GEMM
// C[M,N] = f( mixOpt(A)[M,K] @ WT[N,K]^T ), 128x128 tile, 4 waves, 16x16x32 bf16.
// MODE: 0 none, 1 sigmoid, 2 relu^2. OBF: bf16 output else f32.
template<int MODE, bool MIX, bool OBF>
__global__ __launch_bounds__(256)
void gemm_mfma(const u16* __restrict__ A, const float* __restrict__ mixv,
               const u16* __restrict__ WT, void* __restrict__ Cout,
               int M, int N, int K, int row_off) {
    __shared__ u16 As[128 * 32];
    __shared__ u16 Bs[128 * 32];
    const int tid = threadIdx.x;
    const int m0 = blockIdx.y << 7, n0 = blockIdx.x << 7;
    const int lane = tid & 63, wid = tid >> 6;
    const int wr = wid >> 1, wc = wid & 1;
    const int r16 = lane & 15, g = lane >> 4;

    const int sr = tid >> 1;           // staging row 0..127
    const int sb = (tid & 1) << 1;     // slot base (0 or 2); slot = 8 bf16
    const u16* Arow = A + (size_t)(m0 + sr) * K + sb * 8;
    const u16* Brow = WT + (size_t)(n0 + sr) * K + sb * 8;
    int t = 1;
    if (MIX) t = (row_off + m0 + sr) % T_;

    f32x4 acc[4][4];
#pragma unroll
    for (int i = 0; i < 4; ++i)
#pragma unroll
        for (int j = 0; j < 4; ++j)
#pragma unroll
            for (int q = 0; q < 4; ++q) acc[i][j][q] = 0.f;

    const int wByte0 = sr * 64 + 16 * ((sb) ^ ((sr >> 1) & 3));
    const int wByte1 = sr * 64 + 16 * ((sb + 1) ^ ((sr >> 1) & 3));
    int rA[4], rB[4];
#pragma unroll
    for (int m = 0; m < 4; ++m) {
        int row = wr * 64 + m * 16 + r16;
        rA[m] = row * 64 + 16 * (g ^ ((row >> 1) & 3));
    }
#pragma unroll
    for (int n = 0; n < 4; ++n) {
        int row = wc * 64 + n * 16 + r16;
        rB[n] = row * 64 + 16 * (g ^ ((row >> 1) & 3));
    }

    const int nk = K >> 5;
    for (int kt = 0; kt < nk; ++kt) {
        bf16x8 a0 = *(const bf16x8*)(Arow);
        bf16x8 a1 = *(const bf16x8*)(Arow + 8);
        bf16x8 b0 = *(const bf16x8*)(Brow);
        bf16x8 b1 = *(const bf16x8*)(Brow + 8);
        if constexpr (MIX) {
            bf16x8 p0 = {}, p1 = {};
            if (t > 0) {
                p0 = *(const bf16x8*)(Arow - K);
                p1 = *(const bf16x8*)(Arow - K + 8);
            }
            const float* mv = mixv + (kt << 5) + sb * 8;
            float4 v0 = *(const float4*)(mv);
            float4 v1 = *(const float4*)(mv + 4);
            float4 v2 = *(const float4*)(mv + 8);
            float4 v3 = *(const float4*)(mv + 12);
            float mm0[8] = {v0.x, v0.y, v0.z, v0.w, v1.x, v1.y, v1.z, v1.w};
            float mm1[8] = {v2.x, v2.y, v2.z, v2.w, v3.x, v3.y, v3.z, v3.w};
#pragma unroll
            for (int j = 0; j < 8; ++j) {
                float c = b2f((u16)a0[j]);
                float p = (t > 0) ? b2f((u16)p0[j]) : 0.f;
                a0[j] = (short)f2b(p + mm0[j] * (c - p));
                float c1 = b2f((u16)a1[j]);
                float q = (t > 0) ? b2f((u16)p1[j]) : 0.f;
                a1[j] = (short)f2b(q + mm1[j] * (c1 - q));
            }
        }
        __syncthreads();
        *(bf16x8*)((char*)As + wByte0) = a0;
        *(bf16x8*)((char*)As + wByte1) = a1;
        *(bf16x8*)((char*)Bs + wByte0) = b0;
        *(bf16x8*)((char*)Bs + wByte1) = b1;
        __syncthreads();
        bf16x8 af[4], bg[4];
#pragma unroll
        for (int m = 0; m < 4; ++m) af[m] = *(const bf16x8*)((char*)As + rA[m]);
#pragma unroll
        for (int n = 0; n < 4; ++n) bg[n] = *(const bf16x8*)((char*)Bs + rB[n]);
#pragma unroll
        for (int m = 0; m < 4; ++m)
#pragma unroll
            for (int n = 0; n < 4; ++n)
                acc[m][n] = __builtin_amdgcn_mfma_f32_16x16x32_bf16(af[m], bg[n], acc[m][n], 0, 0, 0);
        Arow += 32;
        Brow += 32;
    }

#pragma unroll
    for (int m = 0; m < 4; ++m)
#pragma unroll
        for (int n = 0; n < 4; ++n)
#pragma unroll
            for (int j = 0; j < 4; ++j) {
                int row = m0 + wr * 64 + m * 16 + g * 4 + j;
                int col = n0 + wc * 64 + n * 16 + r16;
                float v = acc[m][n][j];
                if constexpr (MODE == 1) v = 1.f / (1.f + expf(-v));
                if constexpr (MODE == 2) { v = fmaxf(v, 0.f); v = v * v; }
                size_t o = (size_t)row * N + col;
                if constexpr (OBF) ((u16*)Cout)[o] = f2b(v);
                else ((float*)Cout)[o] = v;
            }
}

// ---------------------------------------------------------------- WKV segmented scan
__global__ void wkv_p1(const float* __restrict__ td, const u16* __restrict__ K,
                       const u16* __restrict__ V, float* __restrict__ st) {
    int bc = blockIdx.x * 256 + threadIdx.x;
    int seg = blockIdx.y;
    int b = bc / C_, c = bc - b * C_;
    float w = -expf(td[c]);
    size_t off = (size_t)b * T_ * C_ + (size_t)seg * WSEG * C_ + c;
    float aa = 0.f, bb = 0.f, pp = -1e38f;
    for (int i = 0; i < WSEG; ++i) {
        float kt = b2f(K[off + (size_t)i * C_]);
        float vt = b2f(V[off + (size_t)i * C_]);
        float ww2 = pp + w;
        float p2 = fmaxf(ww2, kt);
        float e1 = expf(ww2 - p2);
        float e2 = expf(kt - p2);
        aa = e1 * aa + e2 * vt;
        bb = e1 * bb + e2;
        pp = p2;
    }
    int sidx = seg * 3 * BC_ + bc;
    st[sidx] = aa; st[sidx + BC_] = bb; st[sidx + 2 * BC_] = pp;
}

__global__ void wkv_p2(const float* __restrict__ td, const float* __restrict__ st,
                       float* __restrict__ ini) {
    int bc = blockIdx.x * 256 + threadIdx.x;
    int c = bc % C_;
    float wL = -expf(td[c]) * (float)WSEG;
    float aa = 0.f, bb = 0.f, pp = -1e38f;
    for (int s = 0; s < NWSEG; ++s) {
        int sidx = s * 3 * BC_ + bc;
        ini[sidx] = aa; ini[sidx + BC_] = bb; ini[sidx + 2 * BC_] = pp;
        float la = st[sidx], lb = st[sidx + BC_], lp = st[sidx + 2 * BC_];
        float ppw = pp + wL;
        float p = fmaxf(ppw, lp);
        float e1 = expf(ppw - p), e2 = expf(lp - p);
        aa = e1 * aa + e2 * la;
        bb = e1 * bb + e2 * lb;
        pp = p;
    }
}

__global__ void wkv_p3(const float* __restrict__ td, const float* __restrict__ tf,
                       const u16* __restrict__ K, const u16* __restrict__ V,
                       const float* __restrict__ ini, u16* __restrict__ Y) {
    int bc = blockIdx.x * 256 + threadIdx.x;
    int seg = blockIdx.y;
    int b = bc / C_, c = bc - b * C_;
    float w = -expf(td[c]);
    float u = tf[c];
    int sidx = seg * 3 * BC_ + bc;
    float aa = ini[sidx], bb = ini[sidx + BC_], pp = ini[sidx + 2 * BC_];
    size_t off = (size_t)b * T_ * C_ + (size_t)seg * WSEG * C_ + c;
    for (int i = 0; i < WSEG; ++i) {
        float kt = b2f(K[off + (size_t)i * C_]);
        float vt = b2f(V[off + (size_t)i * C_]);
        float ww = u + kt;
        float p = fmaxf(pp, ww);
        float e1 = expf(pp - p);
        float e2 = expf(ww - p);
        Y[off + (size_t)i * C_] = f2b((e1 * aa + e2 * vt) / (e1 * bb + e2));
        float ww2 = pp + w;
        float p2 = fmaxf(ww2, kt);
        float e1b = expf(ww2 - p2);
        float e2b = expf(kt - p2);
        aa = e1b * aa + e2b * vt;
        bb = e1b * bb + e2b;
        pp = p2;
    }
}

// ---------------------------------------------------------------- elementwise muls
__global__ void mul_bb(const u16* __restrict__ a, const u16* __restrict__ b,
                       u16* __restrict__ o) {
    size_t i = ((size_t)blockIdx.x * 256 + threadIdx.x) * 8;
    bf16x8 va = *(const bf16x8*)(a + i);
    bf16x8 vb = *(const bf16x8*)(b + i);
    bf16x8 vo;
#pragma unroll
    for (int j = 0; j < 8; ++j)
        vo[j] = (short)f2b(b2f((u16)va[j]) * b2f((u16)vb[j]));
    *(bf16x8*)(o + i) = vo;
}

__global__ void mul_bf(const u16* __restrict__ a, const float* __restrict__ b,
                       float* __restrict__ o) {
    size_t i = ((size_t)blockIdx.x * 256 + threadIdx.x) * 4;
    ushort4 va = *(const ushort4*)(a + i);
    float4 vb = *(const float4*)(b + i);
    float4 vo;
    vo.x = b2f(va.x) * vb.x; vo.y = b2f(va.y) * vb.y;
    vo.z = b2f(va.z) * vb.z; vo.w = b2f(va.w) * vb.w;
    *(float4*)(o + i) = vo;
}

// ---------------------------------------------------------------- LIF + residual (segmented, warm-up)
__global__ void lif_add(const float* __restrict__ cur, const float* __restrict__ base,
                        float* __restrict__ out) {
    int bc = blockIdx.x * 256 + threadIdx.x;
    int seg = blockIdx.y;
    int b = bc / C_, c = bc - b * C_;
    size_t rowbase = (size_t)b * T_ * C_ + c;
    int t0 = seg * LSEG;
    int tw = t0 - LWARM; if (tw < 0) tw = 0;
    float v = 0.f;
    for (int tt = tw; tt < t0 + LSEG; ++tt) {
        float xt = cur[rowbase + (size_t)tt * C_];
        v = v + (xt - v) * 0.5f;
        float s = (v >= 1.0f) ? 1.f : 0.f;
        if (tt >= t0) out[rowbase + (size_t)tt * C_] = base[rowbase + (size_t)tt * C_] + s;
        if (s > 0.f) v = 0.f;
    }
}

// ---------------------------------------------------------------- launcher
extern "C" void kernel_launch(void* const* d_in, const int* in_sizes, int n_in,
                              void* d_out, int out_size, void* d_ws, size_t ws_size,
                              hipStream_t stream) {
    const float* x    = (const float*)d_in[0];
    const float* ln1w = (const float*)d_in[1];
    const float* ln1b = (const float*)d_in[2];
    const float* ln2w = (const float*)d_in[3];
    const float* ln2b = (const float*)d_in[4];
    const float* td   = (const float*)d_in[5];
    const float* tf   = (const float*)d_in[6];
    const float* amk  = (const float*)d_in[7];
    const float* amv  = (const float*)d_in[8];
    const float* amr  = (const float*)d_in[9];
    const float* aWk  = (const float*)d_in[10];
    const float* aWv  = (const float*)d_in[11];
    const float* aWr  = (const float*)d_in[12];
    const float* aWo  = (const float*)d_in[13];
    const float* fmk  = (const float*)d_in[14];
    const float* fmr  = (const float*)d_in[15];
    const float* fWk  = (const float*)d_in[16];
    const float* fWv  = (const float*)d_in[17];
    const float* fWr  = (const float*)d_in[18];
    float* out = (float*)d_out;

    u16* WkT = (u16*)d_ws;                 // [768][768]
    u16* WvT = WkT + 589824;
    u16* WrT = WvT + 589824;
    u16* WoT = WrT + 589824;
    u16* FkT = WoT + 589824;               // [3072][768]
    u16* FvT = FkT + 2359296;              // [768][3072]
    u16* FrT = FvT + 2359296;              // [768][768]
    float* st  = (float*)(FrT + 589824);   // NWSEG*3*BC_
    float* ini = st + NWSEG * 3 * BC_;
    char* pool = (char*)(ini + NWSEG * 3 * BC_);
    pool = (char*)(((uintptr_t)pool + 255) & ~(uintptr_t)255);
    const size_t SLOT = (size_t)BT_ * C_ * 2;  // 25.17 MB
    u16* S0 = (u16*)pool;
    u16* S1 = (u16*)(pool + SLOT);
    u16* S2 = (u16*)(pool + 2 * SLOT);
    u16* S3 = (u16*)(pool + 3 * SLOT);

    // 0. transpose-cast weights to bf16 [N][K]
    tcast<<<dim3(24, 24), 256, 0, stream>>>(aWk, WkT, 768, 768);
    tcast<<<dim3(24, 24), 256, 0, stream>>>(aWv, WvT, 768, 768);
    tcast<<<dim3(24, 24), 256, 0, stream>>>(aWr, WrT, 768, 768);
    tcast<<<dim3(24, 24), 256, 0, stream>>>(aWo, WoT, 768, 768);
    tcast<<<dim3(96, 24), 256, 0, stream>>>(fWk, FkT, 768, 3072);   // [768][3072] -> [3072][768]
    tcast<<<dim3(24, 96), 256, 0, stream>>>(fWv, FvT, 3072, 768);   // [3072][768] -> [768][3072]
    tcast<<<dim3(24, 24), 256, 0, stream>>>(fWr, FrT, 768, 768);

    dim3 gP(6, 128);
    // 1. L1 = ln1(x)
    ln_kernel<<<BT_, 256, 0, stream>>>(x, ln1w, ln1b, S0);
    // 2-4. K, V, sigmoid(R) with fused token-shift mix
    gemm_mfma<0, true, true><<<gP, 256, 0, stream>>>(S0, amk, WkT, S1, BT_, C_, C_, 0);
    gemm_mfma<0, true, true><<<gP, 256, 0, stream>>>(S0, amv, WvT, S2, BT_, C_, C_, 0);
    gemm_mfma<1, true, true><<<gP, 256, 0, stream>>>(S0, amr, WrT, (u16*)d_out, BT_, C_, C_, 0);
    // 5. Y = wkv(K,V) -> S3 (3-pass segmented scan)
    wkv_p1<<<dim3(BC_ / 256, NWSEG), 256, 0, stream>>>(td, S1, S2, st);
    wkv_p2<<<BC_ / 256, 256, 0, stream>>>(td, st, ini);
    wkv_p3<<<dim3(BC_ / 256, NWSEG), 256, 0, stream>>>(td, tf, S1, S2, ini, S3);
    // 6. RY = R * Y -> S1
    mul_bb<<<(BT_ * C_) / 8 / 256, 256, 0, stream>>>((u16*)d_out, S3, S1);
    // 7. A_out = RY @ Wo -> f32 in S2..S3
    gemm_mfma<0, false, false><<<gP, 256, 0, stream>>>(S1, nullptr, WoT, (float*)S2, BT_, C_, C_, 0);
    // 8. X2 = x + lif(A_out) -> d_out
    lif_add<<<dim3(BC_ / 256, NLSEG), 256, 0, stream>>>((float*)S2, x, out);
    // 9. L2 = ln2(X2) -> S0
    ln_kernel<<<BT_, 256, 0, stream>>>(out, ln2w, ln2b, S0);
    // 10. RRs = sigmoid(mix_r(L2) @ Wr) -> S1
    gemm_mfma<1, true, true><<<gP, 256, 0, stream>>>(S0, fmr, FrT, S1, BT_, C_, C_, 0);
    // 11. FFN per 4096-row chunk (= 2 batches)
    for (int ch = 0; ch < 2; ++ch) {
        const u16* l2p = S0 + (size_t)ch * 4096 * C_;
        dim3 g1(H_ / 128, 32);
        gemm_mfma<2, true, true><<<g1, 256, 0, stream>>>(l2p, fmk, FkT, S2, 4096, H_, C_, ch * 4096);
        dim3 g2(6, 32);
        gemm_mfma<0, false, false><<<g2, 256, 0, stream>>>(S2, nullptr, FvT, (float*)S3, 4096, C_, H_, 0);
        mul_bf<<<(4096 * C_) / 4 / 256, 256, 0, stream>>>(S1 + (size_t)ch * 4096 * C_, (float*)S3, (float*)S3);
        lif_add<<<dim3((2 * C_) / 256, NLSEG), 256, 0, stream>>>((float*)S3,
                                                                 out + (size_t)ch * 4096 * C_,
                                                                 out + (size_t)ch * 4096 * C_);
    }
}

// Round 4
// 723.102 us; speedup vs baseline: 9.3324x; 1.6133x over previous
//
#include <hip/hip_runtime.h>

#define B_ 8
#define T_ 2048
#define C_ 768
#define H_ 3072
#define BT_ (B_ * T_)
#define BC_ (B_ * C_)
#define WSEG 128
#define NWSEG 16
#define LSEG 128
#define NLSEG 16
#define LWARM 96

typedef unsigned short u16;
typedef short bf16x8 __attribute__((ext_vector_type(8)));
typedef float f32x4 __attribute__((ext_vector_type(4)));

__device__ __forceinline__ float b2f(u16 u) {
    union { unsigned i; float f; } w; w.i = ((unsigned)u) << 16; return w.f;
}
__device__ __forceinline__ u16 f2b(float f) {
    union { float f; unsigned i; } w; w.f = f;
    return (u16)((w.i + 0x7fffu + ((w.i >> 16) & 1u)) >> 16);
}

typedef __attribute__((address_space(3))) unsigned int lds_u32;
typedef const __attribute__((address_space(1))) unsigned int glb_u32;
__device__ __forceinline__ void gld_lds16(const void* g, void* l) {
    __builtin_amdgcn_global_load_lds((glb_u32*)g, (lds_u32*)l, 16, 0, 0);
}

// ------------------------------------------------ LayerNorm + token-shift mix (f32 in, bf16 out)
template<int NOUT>
__global__ void lnmix(const float* __restrict__ x, const float* __restrict__ w,
                      const float* __restrict__ b,
                      const float* __restrict__ m1, const float* __restrict__ m2,
                      const float* __restrict__ m3,
                      u16* __restrict__ o1, u16* __restrict__ o2, u16* __restrict__ o3) {
    int row = blockIdx.x;
    int t = row % T_;
    const float* xr = x + (size_t)row * C_;
    const float* xp = xr - C_;
    int tid = threadIdx.x;
    float s = 0.f, s2 = 0.f, ps = 0.f, ps2 = 0.f;
    for (int i = tid; i < C_; i += 256) {
        float v = xr[i]; s += v; s2 += v * v;
        if (t > 0) { float u = xp[i]; ps += u; ps2 += u * u; }
    }
    for (int off = 32; off > 0; off >>= 1) {
        s += __shfl_down(s, off);  s2 += __shfl_down(s2, off);
        ps += __shfl_down(ps, off); ps2 += __shfl_down(ps2, off);
    }
    __shared__ float red[4][4];
    int wid = tid >> 6, lane = tid & 63;
    if (lane == 0) { red[wid][0] = s; red[wid][1] = s2; red[wid][2] = ps; red[wid][3] = ps2; }
    __syncthreads();
    if (tid == 0) {
        float a0 = 0, a1 = 0, a2 = 0, a3 = 0;
        for (int i = 0; i < 4; ++i) { a0 += red[i][0]; a1 += red[i][1]; a2 += red[i][2]; a3 += red[i][3]; }
        red[0][0] = a0; red[0][1] = a1; red[0][2] = a2; red[0][3] = a3;
    }
    __syncthreads();
    float mu = red[0][0] * (1.f / C_);
    float rs = rsqrtf(red[0][1] * (1.f / C_) - mu * mu + 1e-5f);
    float pmu = red[0][2] * (1.f / C_);
    float prs = rsqrtf(red[0][3] * (1.f / C_) - pmu * pmu + 1e-5f);
    size_t ob = (size_t)row * C_;
    for (int i = tid; i < C_; i += 256) {
        float wi = w[i], bi = b[i];
        float n = (xr[i] - mu) * rs * wi + bi;
        float np = (t > 0) ? (xp[i] - pmu) * prs * wi + bi : 0.f;
        o1[ob + i] = f2b(fmaf(m1[i], n - np, np));
        o2[ob + i] = f2b(fmaf(m2[i], n - np, np));
        if constexpr (NOUT == 3) o3[ob + i] = f2b(fmaf(m3[i], n - np, np));
    }
}

// ------------------------------------------------ transpose-cast f32[R][N] -> bf16[N][R]
__global__ void tcast(const float* __restrict__ src, u16* __restrict__ dst, int R, int Ncol) {
    __shared__ float t[32][33];
    int c0 = blockIdx.x * 32, r0 = blockIdx.y * 32;
    int col = threadIdx.x & 31, rw = threadIdx.x >> 5;
#pragma unroll
    for (int i = 0; i < 4; ++i) {
        int r = rw + i * 8;
        t[r][col] = src[(size_t)(r0 + r) * Ncol + c0 + col];
    }
    __syncthreads();
#pragma unroll
    for (int i = 0; i < 4; ++i) {
        int r = rw + i * 8;
        dst[(size_t)(c0 + r) * R + r0 + col] = f2b(t[col][r]);
    }
}

// ------------------------------------------------ bf16 MFMA GEMM (m97 structure)
// C[M,N] = f( A[M,K] @ WT[N,K]^T ).  MODE: 0 none, 1 sigmoid, 2 relu^2.
// OBF: bf16 out else f32.  EMUL: multiply by bf16 gate Emul[row*N+col] before store.
template<int MODE, bool OBF, bool EMUL>
__global__ __launch_bounds__(256)
void gemm2(const u16* __restrict__ A, const u16* __restrict__ WT,
           void* __restrict__ Cout, const u16* __restrict__ Emul, int N, int K) {
    __shared__ u16 As[128 * 32];
    __shared__ u16 Bs[128 * 32];
    const int tid = threadIdx.x;
    const int m0 = blockIdx.y << 7, n0 = blockIdx.x << 7;
    const int lane = tid & 63, wid = tid >> 6;
    const int wr = wid >> 1, wc = wid & 1;
    const int r16 = lane & 15, g = lane >> 4;

    // staging: thread owns LDS elems [tid*8, +8) and [2048 + tid*8, +8) per matrix
    const int srow = tid >> 2;                 // 0..63
    const int sslot = tid & 3;
    const int sx = (srow & 3) ^ ((srow >> 2) & 3);   // same for srow and srow+64
    const u16* gA0 = A + (size_t)(m0 + srow) * K + (sslot ^ sx) * 8;
    const u16* gA1 = gA0 + (size_t)64 * K;
    const u16* gB0 = WT + (size_t)(n0 + srow) * K + (sslot ^ sx) * 8;
    const u16* gB1 = gB0 + (size_t)64 * K;
    u16* lA0 = As + tid * 8;
    u16* lA1 = As + 2048 + tid * 8;
    u16* lB0 = Bs + tid * 8;
    u16* lB1 = Bs + 2048 + tid * 8;

    // fragment read offsets (u16 elements), swizzled
    int offA[4], offB[4];
#pragma unroll
    for (int m = 0; m < 4; ++m) {
        int row = wr * 64 + m * 16 + r16;
        offA[m] = row * 32 + (g ^ (row & 3) ^ ((row >> 2) & 3)) * 8;
        int rob = wc * 64 + m * 16 + r16;
        offB[m] = rob * 32 + (g ^ (rob & 3) ^ ((rob >> 2) & 3)) * 8;
    }

    f32x4 acc[4][4];
#pragma unroll
    for (int i = 0; i < 4; ++i)
#pragma unroll
        for (int j = 0; j < 4; ++j)
#pragma unroll
            for (int q = 0; q < 4; ++q) acc[i][j][q] = 0.f;

    const int nk = K >> 5;
    for (int kt = 0; kt < nk; ++kt) {
        __syncthreads();
        gld_lds16(gA0, lA0);
        gld_lds16(gA1, lA1);
        gld_lds16(gB0, lB0);
        gld_lds16(gB1, lB1);
        gA0 += 32; gA1 += 32; gB0 += 32; gB1 += 32;
        __syncthreads();
        bf16x8 af[4], bg[4];
#pragma unroll
        for (int m = 0; m < 4; ++m) af[m] = *(const bf16x8*)(As + offA[m]);
#pragma unroll
        for (int n = 0; n < 4; ++n) bg[n] = *(const bf16x8*)(Bs + offB[n]);
#pragma unroll
        for (int m = 0; m < 4; ++m)
#pragma unroll
            for (int n = 0; n < 4; ++n)
                acc[m][n] = __builtin_amdgcn_mfma_f32_16x16x32_bf16(af[m], bg[n], acc[m][n], 0, 0, 0);
    }

#pragma unroll
    for (int m = 0; m < 4; ++m)
#pragma unroll
        for (int n = 0; n < 4; ++n)
#pragma unroll
            for (int j = 0; j < 4; ++j) {
                int row = m0 + wr * 64 + m * 16 + g * 4 + j;
                int col = n0 + wc * 64 + n * 16 + r16;
                float v = acc[m][n][j];
                if constexpr (MODE == 1) v = 1.f / (1.f + expf(-v));
                if constexpr (MODE == 2) { v = fmaxf(v, 0.f); v = v * v; }
                size_t o = (size_t)row * N + col;
                if constexpr (EMUL) v *= b2f(Emul[o]);
                if constexpr (OBF) ((u16*)Cout)[o] = f2b(v);
                else ((float*)Cout)[o] = v;
            }
}

// ------------------------------------------------ WKV segmented scan
__global__ void wkv_p1(const float* __restrict__ td, const u16* __restrict__ K,
                       const u16* __restrict__ V, float* __restrict__ st) {
    int bc = blockIdx.x * 256 + threadIdx.x;
    int seg = blockIdx.y;
    int b = bc / C_, c = bc - b * C_;
    float w = -expf(td[c]);
    size_t off = (size_t)b * T_ * C_ + (size_t)seg * WSEG * C_ + c;
    float aa = 0.f, bb = 0.f, pp = -1e38f;
#pragma unroll 4
    for (int i = 0; i < WSEG; ++i) {
        float kt = b2f(K[off + (size_t)i * C_]);
        float vt = b2f(V[off + (size_t)i * C_]);
        float ww2 = pp + w;
        float p2 = fmaxf(ww2, kt);
        float e1 = expf(ww2 - p2);
        float e2 = expf(kt - p2);
        aa = e1 * aa + e2 * vt;
        bb = e1 * bb + e2;
        pp = p2;
    }
    int sidx = seg * 3 * BC_ + bc;
    st[sidx] = aa; st[sidx + BC_] = bb; st[sidx + 2 * BC_] = pp;
}

__global__ void wkv_p2(const float* __restrict__ td, const float* __restrict__ st,
                       float* __restrict__ ini) {
    int bc = blockIdx.x * 256 + threadIdx.x;
    int c = bc % C_;
    float wL = -expf(td[c]) * (float)WSEG;
    float aa = 0.f, bb = 0.f, pp = -1e38f;
    for (int s = 0; s < NWSEG; ++s) {
        int sidx = s * 3 * BC_ + bc;
        ini[sidx] = aa; ini[sidx + BC_] = bb; ini[sidx + 2 * BC_] = pp;
        float la = st[sidx], lb = st[sidx + BC_], lp = st[sidx + 2 * BC_];
        float ppw = pp + wL;
        float p = fmaxf(ppw, lp);
        float e1 = expf(ppw - p), e2 = expf(lp - p);
        aa = e1 * aa + e2 * la;
        bb = e1 * bb + e2 * lb;
        pp = p;
    }
}

__global__ void wkv_p3(const float* __restrict__ td, const float* __restrict__ tf,
                       const u16* __restrict__ K, const u16* __restrict__ V,
                       const float* __restrict__ ini, u16* __restrict__ Y) {
    int bc = blockIdx.x * 256 + threadIdx.x;
    int seg = blockIdx.y;
    int b = bc / C_, c = bc - b * C_;
    float w = -expf(td[c]);
    float u = tf[c];
    int sidx = seg * 3 * BC_ + bc;
    float aa = ini[sidx], bb = ini[sidx + BC_], pp = ini[sidx + 2 * BC_];
    size_t off = (size_t)b * T_ * C_ + (size_t)seg * WSEG * C_ + c;
#pragma unroll 4
    for (int i = 0; i < WSEG; ++i) {
        float kt = b2f(K[off + (size_t)i * C_]);
        float vt = b2f(V[off + (size_t)i * C_]);
        float ww = u + kt;
        float p = fmaxf(pp, ww);
        float e1 = expf(pp - p);
        float e2 = expf(ww - p);
        Y[off + (size_t)i * C_] = f2b((e1 * aa + e2 * vt) / (e1 * bb + e2));
        float ww2 = pp + w;
        float p2 = fmaxf(ww2, kt);
        float e1b = expf(ww2 - p2);
        float e2b = expf(kt - p2);
        aa = e1b * aa + e2b * vt;
        bb = e1b * bb + e2b;
        pp = p2;
    }
}

// ------------------------------------------------ R*Y elementwise (bf16)
__global__ void mul_bb(const u16* __restrict__ a, const u16* __restrict__ b,
                       u16* __restrict__ o) {
    size_t i = ((size_t)blockIdx.x * 256 + threadIdx.x) * 8;
    bf16x8 va = *(const bf16x8*)(a + i);
    bf16x8 vb = *(const bf16x8*)(b + i);
    bf16x8 vo;
#pragma unroll
    for (int j = 0; j < 8; ++j)
        vo[j] = (short)f2b(b2f((u16)va[j]) * b2f((u16)vb[j]));
    *(bf16x8*)(o + i) = vo;
}

// ------------------------------------------------ LIF + residual (segmented, warm-up, pipelined)
__global__ void lif_add(const float* __restrict__ cur, const float* __restrict__ base,
                        float* __restrict__ out) {
    int bc = blockIdx.x * 256 + threadIdx.x;
    int seg = blockIdx.y;
    int b = bc / C_, c = bc - b * C_;
    size_t rowbase = (size_t)b * T_ * C_ + c;
    int t0 = seg * LSEG;
    int tw = t0 - LWARM; if (tw < 0) tw = 0;
    int nw = t0 - tw;
    float v = 0.f;
    const float* cp = cur + rowbase + (size_t)tw * C_;
#pragma unroll 8
    for (int i = 0; i < nw; ++i) {
        float xt = cp[(size_t)i * C_];
        v += (xt - v) * 0.5f;
        v = (v >= 1.f) ? 0.f : v;
    }
    const float* c2 = cur + rowbase + (size_t)t0 * C_;
    const float* bp = base + rowbase + (size_t)t0 * C_;
    float* op = out + rowbase + (size_t)t0 * C_;
#pragma unroll 8
    for (int i = 0; i < LSEG; ++i) {
        float xt = c2[(size_t)i * C_];
        v += (xt - v) * 0.5f;
        float sp = (v >= 1.f) ? 1.f : 0.f;
        op[(size_t)i * C_] = bp[(size_t)i * C_] + sp;
        v = (sp > 0.f) ? 0.f : v;
    }
}

// ------------------------------------------------ launcher
extern "C" void kernel_launch(void* const* d_in, const int* in_sizes, int n_in,
                              void* d_out, int out_size, void* d_ws, size_t ws_size,
                              hipStream_t stream) {
    const float* x    = (const float*)d_in[0];
    const float* ln1w = (const float*)d_in[1];
    const float* ln1b = (const float*)d_in[2];
    const float* ln2w = (const float*)d_in[3];
    const float* ln2b = (const float*)d_in[4];
    const float* td   = (const float*)d_in[5];
    const float* tf   = (const float*)d_in[6];
    const float* amk  = (const float*)d_in[7];
    const float* amv  = (const float*)d_in[8];
    const float* amr  = (const float*)d_in[9];
    const float* aWk  = (const float*)d_in[10];
    const float* aWv  = (const float*)d_in[11];
    const float* aWr  = (const float*)d_in[12];
    const float* aWo  = (const float*)d_in[13];
    const float* fmk  = (const float*)d_in[14];
    const float* fmr  = (const float*)d_in[15];
    const float* fWk  = (const float*)d_in[16];
    const float* fWv  = (const float*)d_in[17];
    const float* fWr  = (const float*)d_in[18];
    float* out = (float*)d_out;

    const size_t NBC = (size_t)BT_ * C_;      // 12,582,912
    u16* WkT = (u16*)d_ws;
    u16* WvT = WkT + 589824;
    u16* WrT = WvT + 589824;
    u16* WoT = WrT + 589824;
    u16* FrT = WoT + 589824;
    u16* FkT = FrT + 589824;                  // [3072][768]
    u16* FvT = FkT + 2359296;                 // [768][3072]
    float* st  = (float*)(FvT + 2359296);
    float* ini = st + NWSEG * 3 * BC_;
    u16* S0 = (u16*)(ini + NWSEG * 3 * BC_);
    u16* S1 = S0 + NBC;
    u16* S2 = S1 + NBC;
    u16* S3 = S2 + NBC;
    char* tail = (char*)(S3 + NBC);           // extra region after S3
    size_t used_fixed = (size_t)((char*)tail - (char*)d_ws);

    // FFN chunking: H lives at S3 (+ tail if needed); F f32 after H.
    int NCH = 4;
    {
        size_t need1 = used_fixed - NBC * 2 /*S3 reused*/ + (size_t)BT_ * H_ * 2 + (size_t)BT_ * C_ * 4;
        size_t need2 = used_fixed - NBC * 2 + (size_t)(BT_ / 2) * H_ * 2 + (size_t)(BT_ / 2) * C_ * 4;
        if (ws_size >= need1) NCH = 1;
        else if (ws_size >= need2) NCH = 2;
    }
    const int CH = BT_ / NCH;
    u16* Hbuf = S3;
    float* Fbuf = (float*)(S3 + (size_t)CH * H_);

    u16* Kb = (u16*)d_out;
    u16* Vb = Kb + NBC;

    // 0. weights -> bf16 [N][K]
    tcast<<<dim3(24, 24), 256, 0, stream>>>(aWk, WkT, 768, 768);
    tcast<<<dim3(24, 24), 256, 0, stream>>>(aWv, WvT, 768, 768);
    tcast<<<dim3(24, 24), 256, 0, stream>>>(aWr, WrT, 768, 768);
    tcast<<<dim3(24, 24), 256, 0, stream>>>(aWo, WoT, 768, 768);
    tcast<<<dim3(24, 24), 256, 0, stream>>>(fWr, FrT, 768, 768);
    tcast<<<dim3(96, 24), 256, 0, stream>>>(fWk, FkT, 768, 3072);
    tcast<<<dim3(24, 96), 256, 0, stream>>>(fWv, FvT, 3072, 768);

    // 1. xk,xv,xr = mix(ln1(x))
    lnmix<3><<<BT_, 256, 0, stream>>>(x, ln1w, ln1b, amk, amv, amr, S0, S1, S2);
    // 2-4. projections
    dim3 gP(6, 128);
    gemm2<0, true, false><<<gP, 256, 0, stream>>>(S0, WkT, Kb, nullptr, C_, C_);
    gemm2<0, true, false><<<gP, 256, 0, stream>>>(S1, WvT, Vb, nullptr, C_, C_);
    gemm2<1, true, false><<<gP, 256, 0, stream>>>(S2, WrT, S3, nullptr, C_, C_);
    // 5. Y = wkv(K,V) -> S0
    wkv_p1<<<dim3(BC_ / 256, NWSEG), 256, 0, stream>>>(td, Kb, Vb, st);
    wkv_p2<<<BC_ / 256, 256, 0, stream>>>(td, st, ini);
    wkv_p3<<<dim3(BC_ / 256, NWSEG), 256, 0, stream>>>(td, tf, Kb, Vb, ini, S0);
    // 6. RY = R*Y -> S1
    mul_bb<<<(int)(NBC / 8 / 256), 256, 0, stream>>>(S3, S0, S1);
    // 7. A_out = RY @ Wo -> f32 spanning S2,S3
    float* Af = (float*)S2;
    gemm2<0, false, false><<<gP, 256, 0, stream>>>(S1, WoT, Af, nullptr, C_, C_);
    // 8. X2 = x + lif(A_out) -> d_out
    lif_add<<<dim3(BC_ / 256, NLSEG), 256, 0, stream>>>(Af, x, out);
    // 9. xk2 -> S0, xr2 -> S1
    lnmix<2><<<BT_, 256, 0, stream>>>(out, ln2w, ln2b, fmk, fmr, nullptr, S0, S1, nullptr);
    // 10. RR = sigmoid(xr2 @ fWr) -> S2
    gemm2<1, true, false><<<gP, 256, 0, stream>>>(S1, FrT, S2, nullptr, C_, C_);
    // 11. FFN per chunk: H = relu^2(xk2 @ fWk); F = RR * (H @ fWv); out += lif(F)
    for (int ch = 0; ch < NCH; ++ch) {
        const u16* xk2c = S0 + (size_t)ch * CH * C_;
        const u16* rrc  = S2 + (size_t)ch * CH * C_;
        dim3 g1(H_ / 128, CH / 128);
        gemm2<2, true, false><<<g1, 256, 0, stream>>>(xk2c, FkT, Hbuf, nullptr, H_, C_);
        dim3 g2(6, CH / 128);
        gemm2<0, false, true><<<g2, 256, 0, stream>>>(Hbuf, FvT, Fbuf, rrc, C_, H_);
        lif_add<<<dim3((CH / T_) * C_ / 256, NLSEG), 256, 0, stream>>>(
            Fbuf, out + (size_t)ch * CH * C_, out + (size_t)ch * CH * C_);
    }
}

// Round 5
// 690.354 us; speedup vs baseline: 9.7751x; 1.0474x over previous
//
#include <hip/hip_runtime.h>

#define B_ 8
#define T_ 2048
#define C_ 768
#define H_ 3072
#define BT_ (B_ * T_)
#define BC_ (B_ * C_)
#define WSEG 128
#define NWSEG 16
#define LSEG 128
#define NLSEG 16
#define LWARM 96

typedef unsigned short u16;
typedef short bf16x8 __attribute__((ext_vector_type(8)));
typedef float f32x4 __attribute__((ext_vector_type(4)));

__device__ __forceinline__ float b2f(u16 u) {
    union { unsigned i; float f; } w; w.i = ((unsigned)u) << 16; return w.f;
}
__device__ __forceinline__ u16 f2b(float f) {
    union { float f; unsigned i; } w; w.f = f;
    return (u16)((w.i + 0x7fffu + ((w.i >> 16) & 1u)) >> 16);
}

typedef __attribute__((address_space(3))) unsigned int lds_u32;
typedef const __attribute__((address_space(1))) unsigned int glb_u32;
__device__ __forceinline__ void gld_lds16(const void* g, void* l) {
    __builtin_amdgcn_global_load_lds((glb_u32*)g, (lds_u32*)l, 16, 0, 0);
}

// ------------------------------------------------ LayerNorm + token-shift mix (f32 in, bf16 out)
template<int NOUT>
__global__ void lnmix(const float* __restrict__ x, const float* __restrict__ w,
                      const float* __restrict__ b,
                      const float* __restrict__ m1, const float* __restrict__ m2,
                      const float* __restrict__ m3,
                      u16* __restrict__ o1, u16* __restrict__ o2, u16* __restrict__ o3) {
    int row = blockIdx.x;
    int t = row % T_;
    const float* xr = x + (size_t)row * C_;
    const float* xp = xr - C_;
    int tid = threadIdx.x;
    float s = 0.f, s2 = 0.f, ps = 0.f, ps2 = 0.f;
    for (int i = tid; i < C_; i += 256) {
        float v = xr[i]; s += v; s2 += v * v;
        if (t > 0) { float u = xp[i]; ps += u; ps2 += u * u; }
    }
    for (int off = 32; off > 0; off >>= 1) {
        s += __shfl_down(s, off);  s2 += __shfl_down(s2, off);
        ps += __shfl_down(ps, off); ps2 += __shfl_down(ps2, off);
    }
    __shared__ float red[4][4];
    int wid = tid >> 6, lane = tid & 63;
    if (lane == 0) { red[wid][0] = s; red[wid][1] = s2; red[wid][2] = ps; red[wid][3] = ps2; }
    __syncthreads();
    if (tid == 0) {
        float a0 = 0, a1 = 0, a2 = 0, a3 = 0;
        for (int i = 0; i < 4; ++i) { a0 += red[i][0]; a1 += red[i][1]; a2 += red[i][2]; a3 += red[i][3]; }
        red[0][0] = a0; red[0][1] = a1; red[0][2] = a2; red[0][3] = a3;
    }
    __syncthreads();
    float mu = red[0][0] * (1.f / C_);
    float rs = rsqrtf(red[0][1] * (1.f / C_) - mu * mu + 1e-5f);
    float pmu = red[0][2] * (1.f / C_);
    float prs = rsqrtf(red[0][3] * (1.f / C_) - pmu * pmu + 1e-5f);
    size_t ob = (size_t)row * C_;
    for (int i = tid; i < C_; i += 256) {
        float wi = w[i], bi = b[i];
        float n = (xr[i] - mu) * rs * wi + bi;
        float np = (t > 0) ? (xp[i] - pmu) * prs * wi + bi : 0.f;
        o1[ob + i] = f2b(fmaf(m1[i], n - np, np));
        o2[ob + i] = f2b(fmaf(m2[i], n - np, np));
        if constexpr (NOUT == 3) o3[ob + i] = f2b(fmaf(m3[i], n - np, np));
    }
}

// ------------------------------------------------ transpose-cast f32[R][N] -> bf16[N][R]
__global__ void tcast(const float* __restrict__ src, u16* __restrict__ dst, int R, int Ncol) {
    __shared__ float t[32][33];
    int c0 = blockIdx.x * 32, r0 = blockIdx.y * 32;
    int col = threadIdx.x & 31, rw = threadIdx.x >> 5;
#pragma unroll
    for (int i = 0; i < 4; ++i) {
        int r = rw + i * 8;
        t[r][col] = src[(size_t)(r0 + r) * Ncol + c0 + col];
    }
    __syncthreads();
#pragma unroll
    for (int i = 0; i < 4; ++i) {
        int r = rw + i * 8;
        dst[(size_t)(c0 + r) * R + r0 + col] = f2b(t[col][r]);
    }
}

// ------------------------------------------------ bf16 MFMA GEMM (m97 structure + XCD remap)
// C[M,N] = f( A[M,K] @ WT[N,K]^T ).  MODE: 0 none, 1 sigmoid, 2 relu^2.
// OBF: bf16 out else f32.  EMUL: multiply by bf16 gate Emul[row*N+col] before store.
template<int MODE, bool OBF, bool EMUL>
__global__ __launch_bounds__(256)
void gemm2(const u16* __restrict__ A, const u16* __restrict__ WT,
           void* __restrict__ Cout, const u16* __restrict__ Emul, int N, int K) {
    __shared__ u16 As[128 * 32];
    __shared__ u16 Bs[128 * 32];
    const int tid = threadIdx.x;

    // bijective XCD-chunked remap (m204): row-major within an XCD so blocks
    // sharing an A-panel run consecutively on the same XCD's L2.
    const int gx = gridDim.x;
    const int nwg = gx * gridDim.y;
    const int lin = blockIdx.y * gx + blockIdx.x;
    const int q = nwg >> 3, r = nwg & 7;
    const int xcd = lin & 7, pos = lin >> 3;
    const int nid = (xcd < r ? xcd * (q + 1) : r * (q + 1) + (xcd - r) * q) + pos;
    const int m0 = (nid / gx) << 7, n0 = (nid % gx) << 7;

    const int lane = tid & 63, wid = tid >> 6;
    const int wr = wid >> 1, wc = wid & 1;
    const int r16 = lane & 15, g = lane >> 4;

    // staging: thread owns LDS elems [tid*8, +8) and [2048 + tid*8, +8) per matrix
    const int srow = tid >> 2;                 // 0..63
    const int sslot = tid & 3;
    const int sx = (srow >> 1) & 3;            // same for srow and srow+64
    const u16* gA0 = A + (size_t)(m0 + srow) * K + (sslot ^ sx) * 8;
    const u16* gA1 = gA0 + (size_t)64 * K;
    const u16* gB0 = WT + (size_t)(n0 + srow) * K + (sslot ^ sx) * 8;
    const u16* gB1 = gB0 + (size_t)64 * K;
    u16* lA0 = As + tid * 8;
    u16* lA1 = As + 2048 + tid * 8;
    u16* lB0 = Bs + tid * 8;
    u16* lB1 = Bs + 2048 + tid * 8;

    // fragment read offsets (u16 elements), swizzled: slot = g ^ ((row>>1)&3)
    int offA[4], offB[4];
#pragma unroll
    for (int m = 0; m < 4; ++m) {
        int row = wr * 64 + m * 16 + r16;
        offA[m] = row * 32 + (g ^ ((row >> 1) & 3)) * 8;
        int rob = wc * 64 + m * 16 + r16;
        offB[m] = rob * 32 + (g ^ ((rob >> 1) & 3)) * 8;
    }

    f32x4 acc[4][4];
#pragma unroll
    for (int i = 0; i < 4; ++i)
#pragma unroll
        for (int j = 0; j < 4; ++j)
#pragma unroll
            for (int q2 = 0; q2 < 4; ++q2) acc[i][j][q2] = 0.f;

    const int nk = K >> 5;
    for (int kt = 0; kt < nk; ++kt) {
        __syncthreads();
        gld_lds16(gA0, lA0);
        gld_lds16(gA1, lA1);
        gld_lds16(gB0, lB0);
        gld_lds16(gB1, lB1);
        gA0 += 32; gA1 += 32; gB0 += 32; gB1 += 32;
        __syncthreads();
        bf16x8 af[4], bg[4];
#pragma unroll
        for (int m = 0; m < 4; ++m) af[m] = *(const bf16x8*)(As + offA[m]);
#pragma unroll
        for (int n = 0; n < 4; ++n) bg[n] = *(const bf16x8*)(Bs + offB[n]);
#pragma unroll
        for (int m = 0; m < 4; ++m)
#pragma unroll
            for (int n = 0; n < 4; ++n)
                acc[m][n] = __builtin_amdgcn_mfma_f32_16x16x32_bf16(af[m], bg[n], acc[m][n], 0, 0, 0);
    }

#pragma unroll
    for (int m = 0; m < 4; ++m)
#pragma unroll
        for (int n = 0; n < 4; ++n)
#pragma unroll
            for (int j = 0; j < 4; ++j) {
                int row = m0 + wr * 64 + m * 16 + g * 4 + j;
                int col = n0 + wc * 64 + n * 16 + r16;
                float v = acc[m][n][j];
                if constexpr (MODE == 1) v = 1.f / (1.f + expf(-v));
                if constexpr (MODE == 2) { v = fmaxf(v, 0.f); v = v * v; }
                size_t o = (size_t)row * N + col;
                if constexpr (EMUL) v *= b2f(Emul[o]);
                if constexpr (OBF) ((u16*)Cout)[o] = f2b(v);
                else ((float*)Cout)[o] = v;
            }
}

// ------------------------------------------------ WKV segmented scan
__global__ void wkv_p1(const float* __restrict__ td, const u16* __restrict__ K,
                       const u16* __restrict__ V, float* __restrict__ st) {
    int bc = blockIdx.x * 256 + threadIdx.x;
    int seg = blockIdx.y;
    int b = bc / C_, c = bc - b * C_;
    float w = -expf(td[c]);
    size_t off = (size_t)b * T_ * C_ + (size_t)seg * WSEG * C_ + c;
    float aa = 0.f, bb = 0.f, pp = -1e38f;
#pragma unroll 4
    for (int i = 0; i < WSEG; ++i) {
        float kt = b2f(K[off + (size_t)i * C_]);
        float vt = b2f(V[off + (size_t)i * C_]);
        float ww2 = pp + w;
        float p2 = fmaxf(ww2, kt);
        float e1 = expf(ww2 - p2);
        float e2 = expf(kt - p2);
        aa = e1 * aa + e2 * vt;
        bb = e1 * bb + e2;
        pp = p2;
    }
    int sidx = seg * 3 * BC_ + bc;
    st[sidx] = aa; st[sidx + BC_] = bb; st[sidx + 2 * BC_] = pp;
}

__global__ void wkv_p2(const float* __restrict__ td, const float* __restrict__ st,
                       float* __restrict__ ini) {
    int bc = blockIdx.x * 256 + threadIdx.x;
    int c = bc % C_;
    float wL = -expf(td[c]) * (float)WSEG;
    float aa = 0.f, bb = 0.f, pp = -1e38f;
    for (int s = 0; s < NWSEG; ++s) {
        int sidx = s * 3 * BC_ + bc;
        ini[sidx] = aa; ini[sidx + BC_] = bb; ini[sidx + 2 * BC_] = pp;
        float la = st[sidx], lb = st[sidx + BC_], lp = st[sidx + 2 * BC_];
        float ppw = pp + wL;
        float p = fmaxf(ppw, lp);
        float e1 = expf(ppw - p), e2 = expf(lp - p);
        aa = e1 * aa + e2 * la;
        bb = e1 * bb + e2 * lb;
        pp = p;
    }
}

// p3 also applies the sigmoid(R) gate: writes RY = R * y  (R is bf16, already sigmoided)
__global__ void wkv_p3(const float* __restrict__ td, const float* __restrict__ tf,
                       const u16* __restrict__ K, const u16* __restrict__ V,
                       const u16* __restrict__ R, const float* __restrict__ ini,
                       u16* __restrict__ RY) {
    int bc = blockIdx.x * 256 + threadIdx.x;
    int seg = blockIdx.y;
    int b = bc / C_, c = bc - b * C_;
    float w = -expf(td[c]);
    float u = tf[c];
    int sidx = seg * 3 * BC_ + bc;
    float aa = ini[sidx], bb = ini[sidx + BC_], pp = ini[sidx + 2 * BC_];
    size_t off = (size_t)b * T_ * C_ + (size_t)seg * WSEG * C_ + c;
#pragma unroll 4
    for (int i = 0; i < WSEG; ++i) {
        float kt = b2f(K[off + (size_t)i * C_]);
        float vt = b2f(V[off + (size_t)i * C_]);
        float rr = b2f(R[off + (size_t)i * C_]);
        float ww = u + kt;
        float p = fmaxf(pp, ww);
        float e1 = expf(pp - p);
        float e2 = expf(ww - p);
        RY[off + (size_t)i * C_] = f2b(rr * (e1 * aa + e2 * vt) / (e1 * bb + e2));
        float ww2 = pp + w;
        float p2 = fmaxf(ww2, kt);
        float e1b = expf(ww2 - p2);
        float e2b = expf(kt - p2);
        aa = e1b * aa + e2b * vt;
        bb = e1b * bb + e2b;
        pp = p2;
    }
}

// ------------------------------------------------ LIF + residual (segmented, warm-up, pipelined)
__global__ void lif_add(const float* __restrict__ cur, const float* __restrict__ base,
                        float* __restrict__ out) {
    int bc = blockIdx.x * 256 + threadIdx.x;
    int seg = blockIdx.y;
    int b = bc / C_, c = bc - b * C_;
    size_t rowbase = (size_t)b * T_ * C_ + c;
    int t0 = seg * LSEG;
    int tw = t0 - LWARM; if (tw < 0) tw = 0;
    int nw = t0 - tw;
    float v = 0.f;
    const float* cp = cur + rowbase + (size_t)tw * C_;
#pragma unroll 8
    for (int i = 0; i < nw; ++i) {
        float xt = cp[(size_t)i * C_];
        v += (xt - v) * 0.5f;
        v = (v >= 1.f) ? 0.f : v;
    }
    const float* c2 = cur + rowbase + (size_t)t0 * C_;
    const float* bp = base + rowbase + (size_t)t0 * C_;
    float* op = out + rowbase + (size_t)t0 * C_;
#pragma unroll 8
    for (int i = 0; i < LSEG; ++i) {
        float xt = c2[(size_t)i * C_];
        v += (xt - v) * 0.5f;
        float sp = (v >= 1.f) ? 1.f : 0.f;
        op[(size_t)i * C_] = bp[(size_t)i * C_] + sp;
        v = (sp > 0.f) ? 0.f : v;
    }
}

// ------------------------------------------------ launcher
extern "C" void kernel_launch(void* const* d_in, const int* in_sizes, int n_in,
                              void* d_out, int out_size, void* d_ws, size_t ws_size,
                              hipStream_t stream) {
    const float* x    = (const float*)d_in[0];
    const float* ln1w = (const float*)d_in[1];
    const float* ln1b = (const float*)d_in[2];
    const float* ln2w = (const float*)d_in[3];
    const float* ln2b = (const float*)d_in[4];
    const float* td   = (const float*)d_in[5];
    const float* tf   = (const float*)d_in[6];
    const float* amk  = (const float*)d_in[7];
    const float* amv  = (const float*)d_in[8];
    const float* amr  = (const float*)d_in[9];
    const float* aWk  = (const float*)d_in[10];
    const float* aWv  = (const float*)d_in[11];
    const float* aWr  = (const float*)d_in[12];
    const float* aWo  = (const float*)d_in[13];
    const float* fmk  = (const float*)d_in[14];
    const float* fmr  = (const float*)d_in[15];
    const float* fWk  = (const float*)d_in[16];
    const float* fWv  = (const float*)d_in[17];
    const float* fWr  = (const float*)d_in[18];
    float* out = (float*)d_out;

    const size_t NBC = (size_t)BT_ * C_;      // 12,582,912
    u16* WkT = (u16*)d_ws;
    u16* WvT = WkT + 589824;
    u16* WrT = WvT + 589824;
    u16* WoT = WrT + 589824;
    u16* FrT = WoT + 589824;
    u16* FkT = FrT + 589824;                  // [3072][768]
    u16* FvT = FkT + 2359296;                 // [768][3072]
    float* st  = (float*)(FvT + 2359296);
    float* ini = st + NWSEG * 3 * BC_;
    u16* S0 = (u16*)(ini + NWSEG * 3 * BC_);
    u16* S1 = S0 + NBC;
    u16* S2 = S1 + NBC;
    u16* S3 = S2 + NBC;
    char* tail = (char*)(S3 + NBC);
    size_t used_fixed = (size_t)((char*)tail - (char*)d_ws);

    // FFN chunking: H lives at S3 (+ tail if needed); F f32 after H.
    int NCH = 4;
    {
        size_t need1 = used_fixed - NBC * 2 + (size_t)BT_ * H_ * 2 + (size_t)BT_ * C_ * 4;
        size_t need2 = used_fixed - NBC * 2 + (size_t)(BT_ / 2) * H_ * 2 + (size_t)(BT_ / 2) * C_ * 4;
        if (ws_size >= need1) NCH = 1;
        else if (ws_size >= need2) NCH = 2;
    }
    const int CH = BT_ / NCH;
    u16* Hbuf = S3;
    float* Fbuf = (float*)(S3 + (size_t)CH * H_);

    u16* Kb = (u16*)d_out;
    u16* Vb = Kb + NBC;

    // 0. weights -> bf16 [N][K]
    tcast<<<dim3(24, 24), 256, 0, stream>>>(aWk, WkT, 768, 768);
    tcast<<<dim3(24, 24), 256, 0, stream>>>(aWv, WvT, 768, 768);
    tcast<<<dim3(24, 24), 256, 0, stream>>>(aWr, WrT, 768, 768);
    tcast<<<dim3(24, 24), 256, 0, stream>>>(aWo, WoT, 768, 768);
    tcast<<<dim3(24, 24), 256, 0, stream>>>(fWr, FrT, 768, 768);
    tcast<<<dim3(96, 24), 256, 0, stream>>>(fWk, FkT, 768, 3072);
    tcast<<<dim3(24, 96), 256, 0, stream>>>(fWv, FvT, 3072, 768);

    // 1. xk,xv,xr = mix(ln1(x))
    lnmix<3><<<BT_, 256, 0, stream>>>(x, ln1w, ln1b, amk, amv, amr, S0, S1, S2);
    // 2-4. projections (K,V to d_out region; sigmoid(R) to S3)
    dim3 gP(6, 128);
    gemm2<0, true, false><<<gP, 256, 0, stream>>>(S0, WkT, Kb, nullptr, C_, C_);
    gemm2<0, true, false><<<gP, 256, 0, stream>>>(S1, WvT, Vb, nullptr, C_, C_);
    gemm2<1, true, false><<<gP, 256, 0, stream>>>(S2, WrT, S3, nullptr, C_, C_);
    // 5. RY = sigmoid(R) * wkv(K,V) -> S0
    wkv_p1<<<dim3(BC_ / 256, NWSEG), 256, 0, stream>>>(td, Kb, Vb, st);
    wkv_p2<<<BC_ / 256, 256, 0, stream>>>(td, st, ini);
    wkv_p3<<<dim3(BC_ / 256, NWSEG), 256, 0, stream>>>(td, tf, Kb, Vb, S3, ini, S0);
    // 6. A_out = RY @ Wo -> f32 spanning S2,S3
    float* Af = (float*)S2;
    gemm2<0, false, false><<<gP, 256, 0, stream>>>(S0, WoT, Af, nullptr, C_, C_);
    // 7. X2 = x + lif(A_out) -> d_out
    lif_add<<<dim3(BC_ / 256, NLSEG), 256, 0, stream>>>(Af, x, out);
    // 8. xk2 -> S0, xr2 -> S1
    lnmix<2><<<BT_, 256, 0, stream>>>(out, ln2w, ln2b, fmk, fmr, nullptr, S0, S1, nullptr);
    // 9. RR = sigmoid(xr2 @ fWr) -> S2
    gemm2<1, true, false><<<gP, 256, 0, stream>>>(S1, FrT, S2, nullptr, C_, C_);
    // 10. FFN per chunk: H = relu^2(xk2 @ fWk); F = RR * (H @ fWv); out += lif(F)
    for (int ch = 0; ch < NCH; ++ch) {
        const u16* xk2c = S0 + (size_t)ch * CH * C_;
        const u16* rrc  = S2 + (size_t)ch * CH * C_;
        dim3 g1(H_ / 128, CH / 128);
        gemm2<2, true, false><<<g1, 256, 0, stream>>>(xk2c, FkT, Hbuf, nullptr, H_, C_);
        dim3 g2(6, CH / 128);
        gemm2<0, false, true><<<g2, 256, 0, stream>>>(Hbuf, FvT, Fbuf, rrc, C_, H_);
        lif_add<<<dim3((CH / T_) * C_ / 256, NLSEG), 256, 0, stream>>>(
            Fbuf, out + (size_t)ch * CH * C_, out + (size_t)ch * CH * C_);
    }
}

// Round 6
// 616.974 us; speedup vs baseline: 10.9377x; 1.1189x over previous
//
#include <hip/hip_runtime.h>

#define B_ 8
#define T_ 2048
#define C_ 768
#define H_ 3072
#define BT_ (B_ * T_)
#define BC_ (B_ * C_)
#define WSEG 128
#define NWSEG 16
#define LSEG 128
#define NLSEG 16
#define LWARM 96

typedef unsigned short u16;
typedef short bf16x8 __attribute__((ext_vector_type(8)));
typedef float f32x4 __attribute__((ext_vector_type(4)));

__device__ __forceinline__ float b2f(u16 u) {
    union { unsigned i; float f; } w; w.i = ((unsigned)u) << 16; return w.f;
}
__device__ __forceinline__ u16 f2b(float f) {
    union { float f; unsigned i; } w; w.f = f;
    return (u16)((w.i + 0x7fffu + ((w.i >> 16) & 1u)) >> 16);
}

typedef __attribute__((address_space(3))) unsigned int lds_u32;
typedef const __attribute__((address_space(1))) unsigned int glb_u32;
__device__ __forceinline__ void gld_lds16(const void* g, void* l) {
    __builtin_amdgcn_global_load_lds((glb_u32*)g, (lds_u32*)l, 16, 0, 0);
}

// ------------------------------------------------ LayerNorm + token-shift mix (f32 in, bf16 out)
template<int NOUT>
__global__ void lnmix(const float* __restrict__ x, const float* __restrict__ w,
                      const float* __restrict__ b,
                      const float* __restrict__ m1, const float* __restrict__ m2,
                      const float* __restrict__ m3,
                      u16* __restrict__ o1, u16* __restrict__ o2, u16* __restrict__ o3) {
    int row = blockIdx.x;
    int t = row % T_;
    const float* xr = x + (size_t)row * C_;
    const float* xp = xr - C_;
    int tid = threadIdx.x;
    float s = 0.f, s2 = 0.f, ps = 0.f, ps2 = 0.f;
    for (int i = tid; i < C_; i += 256) {
        float v = xr[i]; s += v; s2 += v * v;
        if (t > 0) { float u = xp[i]; ps += u; ps2 += u * u; }
    }
    for (int off = 32; off > 0; off >>= 1) {
        s += __shfl_down(s, off);  s2 += __shfl_down(s2, off);
        ps += __shfl_down(ps, off); ps2 += __shfl_down(ps2, off);
    }
    __shared__ float red[4][4];
    int wid = tid >> 6, lane = tid & 63;
    if (lane == 0) { red[wid][0] = s; red[wid][1] = s2; red[wid][2] = ps; red[wid][3] = ps2; }
    __syncthreads();
    if (tid == 0) {
        float a0 = 0, a1 = 0, a2 = 0, a3 = 0;
        for (int i = 0; i < 4; ++i) { a0 += red[i][0]; a1 += red[i][1]; a2 += red[i][2]; a3 += red[i][3]; }
        red[0][0] = a0; red[0][1] = a1; red[0][2] = a2; red[0][3] = a3;
    }
    __syncthreads();
    float mu = red[0][0] * (1.f / C_);
    float rs = rsqrtf(red[0][1] * (1.f / C_) - mu * mu + 1e-5f);
    float pmu = red[0][2] * (1.f / C_);
    float prs = rsqrtf(red[0][3] * (1.f / C_) - pmu * pmu + 1e-5f);
    size_t ob = (size_t)row * C_;
    for (int i = tid; i < C_; i += 256) {
        float wi = w[i], bi = b[i];
        float n = (xr[i] - mu) * rs * wi + bi;
        float np = (t > 0) ? (xp[i] - pmu) * prs * wi + bi : 0.f;
        o1[ob + i] = f2b(fmaf(m1[i], n - np, np));
        o2[ob + i] = f2b(fmaf(m2[i], n - np, np));
        if constexpr (NOUT == 3) o3[ob + i] = f2b(fmaf(m3[i], n - np, np));
    }
}

// ------------------------------------------------ transpose-cast f32[R][N] -> bf16[N][R]
__global__ void tcast(const float* __restrict__ src, u16* __restrict__ dst, int R, int Ncol) {
    __shared__ float t[32][33];
    int c0 = blockIdx.x * 32, r0 = blockIdx.y * 32;
    int col = threadIdx.x & 31, rw = threadIdx.x >> 5;
#pragma unroll
    for (int i = 0; i < 4; ++i) {
        int r = rw + i * 8;
        t[r][col] = src[(size_t)(r0 + r) * Ncol + c0 + col];
    }
    __syncthreads();
#pragma unroll
    for (int i = 0; i < 4; ++i) {
        int r = rw + i * 8;
        dst[(size_t)(c0 + r) * R + r0 + col] = f2b(t[col][r]);
    }
}

// ------------------------------------------------ GEMM core: double-buffered K-loop
// acc += A[m0:+128, :K] @ WT[n0:+128, :K]^T.  As/Bs are 2x4096 u16 LDS buffers.
__device__ __forceinline__ void gemm_core(const u16* __restrict__ A,
                                          const u16* __restrict__ WT,
                                          int K, int m0, int n0,
                                          u16* As, u16* Bs, f32x4 acc[4][4]) {
    const int tid = threadIdx.x;
    const int lane = tid & 63, wid = tid >> 6;
    const int wr = wid >> 1, wc = wid & 1;
    const int r16 = lane & 15, g = lane >> 4;

    const int srow = tid >> 2;
    const int sslot = tid & 3;
    const int sx = (srow >> 1) & 3;
    const u16* gA0 = A + (size_t)(m0 + srow) * K + ((sslot ^ sx) << 3);
    const u16* gA1 = gA0 + (size_t)64 * K;
    const u16* gB0 = WT + (size_t)(n0 + srow) * K + ((sslot ^ sx) << 3);
    const u16* gB1 = gB0 + (size_t)64 * K;
    u16* lA0 = As + tid * 8;
    u16* lA1 = As + 2048 + tid * 8;
    u16* lB0 = Bs + tid * 8;
    u16* lB1 = Bs + 2048 + tid * 8;

    int offA[4], offB[4];
#pragma unroll
    for (int m = 0; m < 4; ++m) {
        int row = wr * 64 + m * 16 + r16;
        offA[m] = row * 32 + (g ^ ((row >> 1) & 3)) * 8;
        int rob = wc * 64 + m * 16 + r16;
        offB[m] = rob * 32 + (g ^ ((rob >> 1) & 3)) * 8;
    }

    // prologue: stage tile 0 into buf 0
    gld_lds16(gA0, lA0); gld_lds16(gA1, lA1);
    gld_lds16(gB0, lB0); gld_lds16(gB1, lB1);
    gA0 += 32; gA1 += 32; gB0 += 32; gB1 += 32;
    __syncthreads();

    const int nk = K >> 5;
    int cur = 0;
    for (int kt = 0; kt < nk; ++kt) {
        const int nxt = cur ^ 1;
        if (kt + 1 < nk) {   // prefetch next tile (overlaps ds_read + MFMA below)
            gld_lds16(gA0, lA0 + nxt * 4096);
            gld_lds16(gA1, lA1 + nxt * 4096);
            gld_lds16(gB0, lB0 + nxt * 4096);
            gld_lds16(gB1, lB1 + nxt * 4096);
            gA0 += 32; gA1 += 32; gB0 += 32; gB1 += 32;
        }
        const u16* Ab = As + cur * 4096;
        const u16* Bb = Bs + cur * 4096;
        bf16x8 af[4], bg[4];
#pragma unroll
        for (int m = 0; m < 4; ++m) af[m] = *(const bf16x8*)(Ab + offA[m]);
#pragma unroll
        for (int n = 0; n < 4; ++n) bg[n] = *(const bf16x8*)(Bb + offB[n]);
#pragma unroll
        for (int m = 0; m < 4; ++m)
#pragma unroll
            for (int n = 0; n < 4; ++n)
                acc[m][n] = __builtin_amdgcn_mfma_f32_16x16x32_bf16(af[m], bg[n], acc[m][n], 0, 0, 0);
        __syncthreads();   // drains prefetch (vmcnt) + keeps buffers coherent
        cur = nxt;
    }
}

// bijective XCD-chunked remap (m204)
__device__ __forceinline__ void xcd_remap(int& m0, int& n0) {
    const int gx = gridDim.x;
    const int nwg = gx * gridDim.y;
    const int lin = blockIdx.y * gx + blockIdx.x;
    const int q = nwg >> 3, r = nwg & 7;
    const int xcd = lin & 7, pos = lin >> 3;
    const int nid = (xcd < r ? xcd * (q + 1) : r * (q + 1) + (xcd - r) * q) + pos;
    m0 = (nid / gx) << 7;
    n0 = (nid % gx) << 7;
}

// ------------------------------------------------ single GEMM
// MODE: 0 none, 1 sigmoid, 2 relu^2.  OBF bf16 out else f32.  EMUL: gate by bf16 Emul.
template<int MODE, bool OBF, bool EMUL>
__global__ __launch_bounds__(256)
void gemm2(const u16* __restrict__ A, const u16* __restrict__ WT,
           void* __restrict__ Cout, const u16* __restrict__ Emul, int N, int K) {
    __shared__ u16 As[8192];
    __shared__ u16 Bs[8192];
    int m0, n0;
    xcd_remap(m0, n0);
    f32x4 acc[4][4];
#pragma unroll
    for (int i = 0; i < 4; ++i)
#pragma unroll
        for (int j = 0; j < 4; ++j)
#pragma unroll
            for (int q = 0; q < 4; ++q) acc[i][j][q] = 0.f;
    gemm_core(A, WT, K, m0, n0, As, Bs, acc);

    const int lane = threadIdx.x & 63, wid = threadIdx.x >> 6;
    const int wr = wid >> 1, wc = wid & 1;
    const int r16 = lane & 15, g = lane >> 4;
#pragma unroll
    for (int m = 0; m < 4; ++m)
#pragma unroll
        for (int n = 0; n < 4; ++n)
#pragma unroll
            for (int j = 0; j < 4; ++j) {
                int row = m0 + wr * 64 + m * 16 + g * 4 + j;
                int col = n0 + wc * 64 + n * 16 + r16;
                float v = acc[m][n][j];
                if constexpr (MODE == 1) v = 1.f / (1.f + expf(-v));
                if constexpr (MODE == 2) { v = fmaxf(v, 0.f); v = v * v; }
                size_t o = (size_t)row * N + col;
                if constexpr (EMUL) v *= b2f(Emul[o]);
                if constexpr (OBF) ((u16*)Cout)[o] = f2b(v);
                else ((float*)Cout)[o] = v;
            }
}

// ------------------------------------------------ fused K/V/R projections (blockIdx.z picks slice)
struct P3 {
    const u16 *A0, *A1, *A2;
    const u16 *W0, *W1, *W2;
    u16 *O0, *O1, *O2;
};
__global__ __launch_bounds__(256)
void proj3(P3 p, int N, int K) {
    __shared__ u16 As[8192];
    __shared__ u16 Bs[8192];
    const int z = blockIdx.z;
    const u16* A = (z == 0) ? p.A0 : (z == 1) ? p.A1 : p.A2;
    const u16* W = (z == 0) ? p.W0 : (z == 1) ? p.W1 : p.W2;
    u16* O = (z == 0) ? p.O0 : (z == 1) ? p.O1 : p.O2;
    int m0, n0;
    xcd_remap(m0, n0);
    f32x4 acc[4][4];
#pragma unroll
    for (int i = 0; i < 4; ++i)
#pragma unroll
        for (int j = 0; j < 4; ++j)
#pragma unroll
            for (int q = 0; q < 4; ++q) acc[i][j][q] = 0.f;
    gemm_core(A, W, K, m0, n0, As, Bs, acc);

    const int lane = threadIdx.x & 63, wid = threadIdx.x >> 6;
    const int wr = wid >> 1, wc = wid & 1;
    const int r16 = lane & 15, g = lane >> 4;
    const bool sig = (z == 2);
#pragma unroll
    for (int m = 0; m < 4; ++m)
#pragma unroll
        for (int n = 0; n < 4; ++n)
#pragma unroll
            for (int j = 0; j < 4; ++j) {
                int row = m0 + wr * 64 + m * 16 + g * 4 + j;
                int col = n0 + wc * 64 + n * 16 + r16;
                float v = acc[m][n][j];
                if (sig) v = 1.f / (1.f + expf(-v));
                O[(size_t)row * N + col] = f2b(v);
            }
}

// ------------------------------------------------ WKV segmented scan
__global__ void wkv_p1(const float* __restrict__ td, const u16* __restrict__ K,
                       const u16* __restrict__ V, float* __restrict__ st) {
    int bc = blockIdx.x * 256 + threadIdx.x;
    int seg = blockIdx.y;
    int b = bc / C_, c = bc - b * C_;
    float w = -expf(td[c]);
    size_t off = (size_t)b * T_ * C_ + (size_t)seg * WSEG * C_ + c;
    float aa = 0.f, bb = 0.f, pp = -1e38f;
#pragma unroll 4
    for (int i = 0; i < WSEG; ++i) {
        float kt = b2f(K[off + (size_t)i * C_]);
        float vt = b2f(V[off + (size_t)i * C_]);
        float ww2 = pp + w;
        float p2 = fmaxf(ww2, kt);
        float e1 = expf(ww2 - p2);
        float e2 = expf(kt - p2);
        aa = e1 * aa + e2 * vt;
        bb = e1 * bb + e2;
        pp = p2;
    }
    int sidx = seg * 3 * BC_ + bc;
    st[sidx] = aa; st[sidx + BC_] = bb; st[sidx + 2 * BC_] = pp;
}

__global__ void wkv_p2(const float* __restrict__ td, const float* __restrict__ st,
                       float* __restrict__ ini) {
    int bc = blockIdx.x * 256 + threadIdx.x;
    int c = bc % C_;
    float wL = -expf(td[c]) * (float)WSEG;
    float aa = 0.f, bb = 0.f, pp = -1e38f;
    for (int s = 0; s < NWSEG; ++s) {
        int sidx = s * 3 * BC_ + bc;
        ini[sidx] = aa; ini[sidx + BC_] = bb; ini[sidx + 2 * BC_] = pp;
        float la = st[sidx], lb = st[sidx + BC_], lp = st[sidx + 2 * BC_];
        float ppw = pp + wL;
        float p = fmaxf(ppw, lp);
        float e1 = expf(ppw - p), e2 = expf(lp - p);
        aa = e1 * aa + e2 * la;
        bb = e1 * bb + e2 * lb;
        pp = p;
    }
}

// p3 applies the sigmoid(R) gate: writes RY = R * y
__global__ void wkv_p3(const float* __restrict__ td, const float* __restrict__ tf,
                       const u16* __restrict__ K, const u16* __restrict__ V,
                       const u16* __restrict__ R, const float* __restrict__ ini,
                       u16* __restrict__ RY) {
    int bc = blockIdx.x * 256 + threadIdx.x;
    int seg = blockIdx.y;
    int b = bc / C_, c = bc - b * C_;
    float w = -expf(td[c]);
    float u = tf[c];
    int sidx = seg * 3 * BC_ + bc;
    float aa = ini[sidx], bb = ini[sidx + BC_], pp = ini[sidx + 2 * BC_];
    size_t off = (size_t)b * T_ * C_ + (size_t)seg * WSEG * C_ + c;
#pragma unroll 4
    for (int i = 0; i < WSEG; ++i) {
        float kt = b2f(K[off + (size_t)i * C_]);
        float vt = b2f(V[off + (size_t)i * C_]);
        float rr = b2f(R[off + (size_t)i * C_]);
        float ww = u + kt;
        float p = fmaxf(pp, ww);
        float e1 = expf(pp - p);
        float e2 = expf(ww - p);
        RY[off + (size_t)i * C_] = f2b(rr * (e1 * aa + e2 * vt) / (e1 * bb + e2));
        float ww2 = pp + w;
        float p2 = fmaxf(ww2, kt);
        float e1b = expf(ww2 - p2);
        float e2b = expf(kt - p2);
        aa = e1b * aa + e2b * vt;
        bb = e1b * bb + e2b;
        pp = p2;
    }
}

// ------------------------------------------------ LIF + residual (segmented, warm-up, pipelined)
__global__ void lif_add(const float* __restrict__ cur, const float* __restrict__ base,
                        float* __restrict__ out) {
    int bc = blockIdx.x * 256 + threadIdx.x;
    int seg = blockIdx.y;
    int b = bc / C_, c = bc - b * C_;
    size_t rowbase = (size_t)b * T_ * C_ + c;
    int t0 = seg * LSEG;
    int tw = t0 - LWARM; if (tw < 0) tw = 0;
    int nw = t0 - tw;
    float v = 0.f;
    const float* cp = cur + rowbase + (size_t)tw * C_;
#pragma unroll 8
    for (int i = 0; i < nw; ++i) {
        float xt = cp[(size_t)i * C_];
        v += (xt - v) * 0.5f;
        v = (v >= 1.f) ? 0.f : v;
    }
    const float* c2 = cur + rowbase + (size_t)t0 * C_;
    const float* bp = base + rowbase + (size_t)t0 * C_;
    float* op = out + rowbase + (size_t)t0 * C_;
#pragma unroll 8
    for (int i = 0; i < LSEG; ++i) {
        float xt = c2[(size_t)i * C_];
        v += (xt - v) * 0.5f;
        float sp = (v >= 1.f) ? 1.f : 0.f;
        op[(size_t)i * C_] = bp[(size_t)i * C_] + sp;
        v = (sp > 0.f) ? 0.f : v;
    }
}

// ------------------------------------------------ launcher
extern "C" void kernel_launch(void* const* d_in, const int* in_sizes, int n_in,
                              void* d_out, int out_size, void* d_ws, size_t ws_size,
                              hipStream_t stream) {
    const float* x    = (const float*)d_in[0];
    const float* ln1w = (const float*)d_in[1];
    const float* ln1b = (const float*)d_in[2];
    const float* ln2w = (const float*)d_in[3];
    const float* ln2b = (const float*)d_in[4];
    const float* td   = (const float*)d_in[5];
    const float* tf   = (const float*)d_in[6];
    const float* amk  = (const float*)d_in[7];
    const float* amv  = (const float*)d_in[8];
    const float* amr  = (const float*)d_in[9];
    const float* aWk  = (const float*)d_in[10];
    const float* aWv  = (const float*)d_in[11];
    const float* aWr  = (const float*)d_in[12];
    const float* aWo  = (const float*)d_in[13];
    const float* fmk  = (const float*)d_in[14];
    const float* fmr  = (const float*)d_in[15];
    const float* fWk  = (const float*)d_in[16];
    const float* fWv  = (const float*)d_in[17];
    const float* fWr  = (const float*)d_in[18];
    float* out = (float*)d_out;

    const size_t NBC = (size_t)BT_ * C_;
    u16* WkT = (u16*)d_ws;
    u16* WvT = WkT + 589824;
    u16* WrT = WvT + 589824;
    u16* WoT = WrT + 589824;
    u16* FrT = WoT + 589824;
    u16* FkT = FrT + 589824;                  // [3072][768]
    u16* FvT = FkT + 2359296;                 // [768][3072]
    float* st  = (float*)(FvT + 2359296);
    float* ini = st + NWSEG * 3 * BC_;
    u16* S0 = (u16*)(ini + NWSEG * 3 * BC_);
    u16* S1 = S0 + NBC;
    u16* S2 = S1 + NBC;
    u16* S3 = S2 + NBC;
    char* tail = (char*)(S3 + NBC);
    size_t used_fixed = (size_t)((char*)tail - (char*)d_ws);

    // FFN chunking: prefer 2 chunks (50MB H-chunk, possible L3 retention)
    int NCH = 4;
    {
        size_t need2 = used_fixed - NBC * 2 + (size_t)(BT_ / 2) * H_ * 2 + (size_t)(BT_ / 2) * C_ * 4;
        if (ws_size >= need2) NCH = 2;
    }
    const int CH = BT_ / NCH;
    u16* Hbuf = S3;
    float* Fbuf = (float*)(S3 + (size_t)CH * H_);

    u16* Kb = (u16*)d_out;
    u16* Vb = Kb + NBC;

    // 0. weights -> bf16 [N][K]
    tcast<<<dim3(24, 24), 256, 0, stream>>>(aWk, WkT, 768, 768);
    tcast<<<dim3(24, 24), 256, 0, stream>>>(aWv, WvT, 768, 768);
    tcast<<<dim3(24, 24), 256, 0, stream>>>(aWr, WrT, 768, 768);
    tcast<<<dim3(24, 24), 256, 0, stream>>>(aWo, WoT, 768, 768);
    tcast<<<dim3(24, 24), 256, 0, stream>>>(fWr, FrT, 768, 768);
    tcast<<<dim3(96, 24), 256, 0, stream>>>(fWk, FkT, 768, 3072);
    tcast<<<dim3(24, 96), 256, 0, stream>>>(fWv, FvT, 3072, 768);

    // 1. xk,xv,xr = mix(ln1(x))
    lnmix<3><<<BT_, 256, 0, stream>>>(x, ln1w, ln1b, amk, amv, amr, S0, S1, S2);
    // 2. K,V,sigmoid(R) in one fused dispatch (z = slice)
    {
        P3 p{S0, S1, S2, WkT, WvT, WrT, Kb, Vb, S3};
        proj3<<<dim3(6, 128, 3), 256, 0, stream>>>(p, C_, C_);
    }
    // 3. RY = sigmoid(R) * wkv(K,V) -> S0
    wkv_p1<<<dim3(BC_ / 256, NWSEG), 256, 0, stream>>>(td, Kb, Vb, st);
    wkv_p2<<<BC_ / 256, 256, 0, stream>>>(td, st, ini);
    wkv_p3<<<dim3(BC_ / 256, NWSEG), 256, 0, stream>>>(td, tf, Kb, Vb, S3, ini, S0);
    // 4. A_out = RY @ Wo -> f32 spanning S2,S3
    float* Af = (float*)S2;
    dim3 gP(6, 128);
    gemm2<0, false, false><<<gP, 256, 0, stream>>>(S0, WoT, Af, nullptr, C_, C_);
    // 5. X2 = x + lif(A_out) -> d_out
    lif_add<<<dim3(BC_ / 256, NLSEG), 256, 0, stream>>>(Af, x, out);
    // 6. xk2 -> S0, xr2 -> S1
    lnmix<2><<<BT_, 256, 0, stream>>>(out, ln2w, ln2b, fmk, fmr, nullptr, S0, S1, nullptr);
    // 7. RR = sigmoid(xr2 @ fWr) -> S2
    gemm2<1, true, false><<<gP, 256, 0, stream>>>(S1, FrT, S2, nullptr, C_, C_);
    // 8. FFN per chunk: H = relu^2(xk2 @ fWk); F = RR * (H @ fWv); out += lif(F)
    for (int ch = 0; ch < NCH; ++ch) {
        const u16* xk2c = S0 + (size_t)ch * CH * C_;
        const u16* rrc  = S2 + (size_t)ch * CH * C_;
        dim3 g1(H_ / 128, CH / 128);
        gemm2<2, true, false><<<g1, 256, 0, stream>>>(xk2c, FkT, Hbuf, nullptr, H_, C_);
        dim3 g2(6, CH / 128);
        gemm2<0, false, true><<<g2, 256, 0, stream>>>(Hbuf, FvT, Fbuf, rrc, C_, H_);
        lif_add<<<dim3((CH / T_) * C_ / 256, NLSEG), 256, 0, stream>>>(
            Fbuf, out + (size_t)ch * CH * C_, out + (size_t)ch * CH * C_);
    }
}

// Round 7
// 592.864 us; speedup vs baseline: 11.3825x; 1.0407x over previous
//
#include <hip/hip_runtime.h>

#define B_ 8
#define T_ 2048
#define C_ 768
#define H_ 3072
#define BT_ (B_ * T_)
#define BC_ (B_ * C_)
#define WSEG 128
#define NWSEG 16
#define LSEG 128
#define NLSEG 16
#define LWARM 96

typedef unsigned short u16;
typedef short bf16x8 __attribute__((ext_vector_type(8)));
typedef float f32x4 __attribute__((ext_vector_type(4)));

__device__ __forceinline__ float b2f(u16 u) {
    union { unsigned i; float f; } w; w.i = ((unsigned)u) << 16; return w.f;
}
__device__ __forceinline__ u16 f2b(float f) {
    union { float f; unsigned i; } w; w.f = f;
    return (u16)((w.i + 0x7fffu + ((w.i >> 16) & 1u)) >> 16);
}

typedef __attribute__((address_space(3))) unsigned int lds_u32;
typedef const __attribute__((address_space(1))) unsigned int glb_u32;
__device__ __forceinline__ void gld_lds16(const void* g, void* l) {
    __builtin_amdgcn_global_load_lds((glb_u32*)g, (lds_u32*)l, 16, 0, 0);
}

// ------------------------------------------------ LayerNorm + token-shift mix (f32 in, bf16 out)
template<int NOUT>
__global__ void lnmix(const float* __restrict__ x, const float* __restrict__ w,
                      const float* __restrict__ b,
                      const float* __restrict__ m1, const float* __restrict__ m2,
                      const float* __restrict__ m3,
                      u16* __restrict__ o1, u16* __restrict__ o2, u16* __restrict__ o3) {
    int row = blockIdx.x;
    int t = row % T_;
    const float* xr = x + (size_t)row * C_;
    const float* xp = xr - C_;
    int tid = threadIdx.x;
    float s = 0.f, s2 = 0.f, ps = 0.f, ps2 = 0.f;
    for (int i = tid; i < C_; i += 256) {
        float v = xr[i]; s += v; s2 += v * v;
        if (t > 0) { float u = xp[i]; ps += u; ps2 += u * u; }
    }
    for (int off = 32; off > 0; off >>= 1) {
        s += __shfl_down(s, off);  s2 += __shfl_down(s2, off);
        ps += __shfl_down(ps, off); ps2 += __shfl_down(ps2, off);
    }
    __shared__ float red[4][4];
    int wid = tid >> 6, lane = tid & 63;
    if (lane == 0) { red[wid][0] = s; red[wid][1] = s2; red[wid][2] = ps; red[wid][3] = ps2; }
    __syncthreads();
    if (tid == 0) {
        float a0 = 0, a1 = 0, a2 = 0, a3 = 0;
        for (int i = 0; i < 4; ++i) { a0 += red[i][0]; a1 += red[i][1]; a2 += red[i][2]; a3 += red[i][3]; }
        red[0][0] = a0; red[0][1] = a1; red[0][2] = a2; red[0][3] = a3;
    }
    __syncthreads();
    float mu = red[0][0] * (1.f / C_);
    float rs = rsqrtf(red[0][1] * (1.f / C_) - mu * mu + 1e-5f);
    float pmu = red[0][2] * (1.f / C_);
    float prs = rsqrtf(red[0][3] * (1.f / C_) - pmu * pmu + 1e-5f);
    size_t ob = (size_t)row * C_;
    for (int i = tid; i < C_; i += 256) {
        float wi = w[i], bi = b[i];
        float n = (xr[i] - mu) * rs * wi + bi;
        float np = (t > 0) ? (xp[i] - pmu) * prs * wi + bi : 0.f;
        o1[ob + i] = f2b(fmaf(m1[i], n - np, np));
        o2[ob + i] = f2b(fmaf(m2[i], n - np, np));
        if constexpr (NOUT == 3) o3[ob + i] = f2b(fmaf(m3[i], n - np, np));
    }
}

// ------------------------------------------------ batched transpose-cast f32[R][N] -> bf16[N][R]
struct TCJ { const float* s; u16* d; int R, Ncol, nbx, b0; };
struct TC7 { TCJ j[7]; };
__global__ void tcast_all(TC7 jobs) {
    __shared__ float t[32][33];
    int bid = blockIdx.x;
    int ji = 0;
#pragma unroll
    for (int k = 1; k < 7; ++k) if (bid >= jobs.j[k].b0) ji = k;
    TCJ jb = jobs.j[ji];
    int local = bid - jb.b0;
    int bx = local % jb.nbx, by = local / jb.nbx;
    int c0 = bx * 32, r0 = by * 32;
    int col = threadIdx.x & 31, rw = threadIdx.x >> 5;
#pragma unroll
    for (int i = 0; i < 4; ++i) {
        int r = rw + i * 8;
        t[r][col] = jb.s[(size_t)(r0 + r) * jb.Ncol + c0 + col];
    }
    __syncthreads();
#pragma unroll
    for (int i = 0; i < 4; ++i) {
        int r = rw + i * 8;
        jb.d[(size_t)(c0 + r) * jb.R + r0 + col] = f2b(t[col][r]);
    }
}

// ------------------------------------------------ GEMM core: 128x256 tile, 4 waves, wave-tile 64x128
// acc += A[m0:+128, :K] @ WT[n0:+256, :K]^T.  As: 2x4096 u16, Bs: 2x8192 u16 (double buffer).
__device__ __forceinline__ void gemm_core(const u16* __restrict__ A,
                                          const u16* __restrict__ WT,
                                          int K, int m0, int n0,
                                          u16* As, u16* Bs, f32x4 acc[4][8]) {
    const int tid = threadIdx.x;
    const int lane = tid & 63, wid = tid >> 6;
    const int wr = wid >> 1, wc = wid & 1;
    const int r16 = lane & 15, g = lane >> 4;

    const int srow = tid >> 2;
    const int sslot = tid & 3;
    const int sx = (srow >> 1) & 3;            // invariant under srow += 64*j
    const u16* gA0 = A + (size_t)(m0 + srow) * K + ((sslot ^ sx) << 3);
    const u16* gA1 = gA0 + (size_t)64 * K;
    const u16* gB0 = WT + (size_t)(n0 + srow) * K + ((sslot ^ sx) << 3);
    const u16* gB1 = gB0 + (size_t)64 * K;
    const u16* gB2 = gB0 + (size_t)128 * K;
    const u16* gB3 = gB0 + (size_t)192 * K;
    u16* lA = As + tid * 8;
    u16* lB = Bs + tid * 8;

    int offA[4], offB[8];
#pragma unroll
    for (int m = 0; m < 4; ++m) {
        int row = wr * 64 + m * 16 + r16;
        offA[m] = row * 32 + (g ^ ((row >> 1) & 3)) * 8;
    }
#pragma unroll
    for (int n = 0; n < 8; ++n) {
        int rob = wc * 128 + n * 16 + r16;
        offB[n] = rob * 32 + (g ^ ((rob >> 1) & 3)) * 8;
    }

    // prologue: stage tile 0 into buffer 0
    gld_lds16(gA0, lA);        gld_lds16(gA1, lA + 2048);
    gld_lds16(gB0, lB);        gld_lds16(gB1, lB + 2048);
    gld_lds16(gB2, lB + 4096); gld_lds16(gB3, lB + 6144);
    gA0 += 32; gA1 += 32; gB0 += 32; gB1 += 32; gB2 += 32; gB3 += 32;
    __syncthreads();

    const int nk = K >> 5;
    int cur = 0;
    for (int kt = 0; kt < nk; ++kt) {
        const int nxt = cur ^ 1;
        if (kt + 1 < nk) {   // prefetch next tile; overlaps ds_read + MFMA below
            u16* pA = lA + nxt * 4096;
            u16* pB = lB + nxt * 8192;
            gld_lds16(gA0, pA);        gld_lds16(gA1, pA + 2048);
            gld_lds16(gB0, pB);        gld_lds16(gB1, pB + 2048);
            gld_lds16(gB2, pB + 4096); gld_lds16(gB3, pB + 6144);
            gA0 += 32; gA1 += 32; gB0 += 32; gB1 += 32; gB2 += 32; gB3 += 32;
        }
        const u16* Ab = As + cur * 4096;
        const u16* Bb = Bs + cur * 8192;
        bf16x8 af[4], bg[8];
#pragma unroll
        for (int m = 0; m < 4; ++m) af[m] = *(const bf16x8*)(Ab + offA[m]);
#pragma unroll
        for (int n = 0; n < 8; ++n) bg[n] = *(const bf16x8*)(Bb + offB[n]);
#pragma unroll
        for (int m = 0; m < 4; ++m)
#pragma unroll
            for (int n = 0; n < 8; ++n)
                acc[m][n] = __builtin_amdgcn_mfma_f32_16x16x32_bf16(af[m], bg[n], acc[m][n], 0, 0, 0);
        __syncthreads();   // drains prefetch + protects buffers
        cur = nxt;
    }
}

// bijective XCD-chunked remap (m204); tile 128 rows x 256 cols
__device__ __forceinline__ void xcd_remap(int& m0, int& n0) {
    const int gx = gridDim.x;
    const int nwg = gx * gridDim.y;
    const int lin = blockIdx.y * gx + blockIdx.x;
    const int q = nwg >> 3, r = nwg & 7;
    const int xcd = lin & 7, pos = lin >> 3;
    const int nid = (xcd < r ? xcd * (q + 1) : r * (q + 1) + (xcd - r) * q) + pos;
    m0 = (nid / gx) << 7;
    n0 = (nid % gx) << 8;
}

// ------------------------------------------------ single GEMM (bf16 out)
// MODE: 0 none, 1 sigmoid, 2 relu^2.  EMUL: multiply by bf16 gate Emul[row*N+col].
template<int MODE, bool EMUL>
__global__ __launch_bounds__(256, 2)
void gemm2(const u16* __restrict__ A, const u16* __restrict__ WT,
           u16* __restrict__ Cout, const u16* __restrict__ Emul, int N, int K) {
    __shared__ u16 As[8192];
    __shared__ u16 Bs[16384];
    int m0, n0;
    xcd_remap(m0, n0);
    f32x4 acc[4][8];
#pragma unroll
    for (int i = 0; i < 4; ++i)
#pragma unroll
        for (int j = 0; j < 8; ++j)
#pragma unroll
            for (int q = 0; q < 4; ++q) acc[i][j][q] = 0.f;
    gemm_core(A, WT, K, m0, n0, As, Bs, acc);

    const int lane = threadIdx.x & 63, wid = threadIdx.x >> 6;
    const int wr = wid >> 1, wc = wid & 1;
    const int r16 = lane & 15, g = lane >> 4;
#pragma unroll
    for (int m = 0; m < 4; ++m)
#pragma unroll
        for (int n = 0; n < 8; ++n)
#pragma unroll
            for (int j = 0; j < 4; ++j) {
                int row = m0 + wr * 64 + m * 16 + g * 4 + j;
                int col = n0 + wc * 128 + n * 16 + r16;
                float v = acc[m][n][j];
                if constexpr (MODE == 1) v = 1.f / (1.f + expf(-v));
                if constexpr (MODE == 2) { v = fmaxf(v, 0.f); v = v * v; }
                size_t o = (size_t)row * N + col;
                if constexpr (EMUL) v *= b2f(Emul[o]);
                Cout[o] = f2b(v);
            }
}

// ------------------------------------------------ fused K/V/R projections (blockIdx.z = slice)
struct P3 {
    const u16 *A0, *A1, *A2;
    const u16 *W0, *W1, *W2;
    u16 *O0, *O1, *O2;
};
__global__ __launch_bounds__(256, 2)
void proj3(P3 p, int N, int K) {
    __shared__ u16 As[8192];
    __shared__ u16 Bs[16384];
    const int z = blockIdx.z;
    const u16* A = (z == 0) ? p.A0 : (z == 1) ? p.A1 : p.A2;
    const u16* W = (z == 0) ? p.W0 : (z == 1) ? p.W1 : p.W2;
    u16* O = (z == 0) ? p.O0 : (z == 1) ? p.O1 : p.O2;
    int m0, n0;
    xcd_remap(m0, n0);
    f32x4 acc[4][8];
#pragma unroll
    for (int i = 0; i < 4; ++i)
#pragma unroll
        for (int j = 0; j < 8; ++j)
#pragma unroll
            for (int q = 0; q < 4; ++q) acc[i][j][q] = 0.f;
    gemm_core(A, W, K, m0, n0, As, Bs, acc);

    const int lane = threadIdx.x & 63, wid = threadIdx.x >> 6;
    const int wr = wid >> 1, wc = wid & 1;
    const int r16 = lane & 15, g = lane >> 4;
    const bool sig = (z == 2);
#pragma unroll
    for (int m = 0; m < 4; ++m)
#pragma unroll
        for (int n = 0; n < 8; ++n)
#pragma unroll
            for (int j = 0; j < 4; ++j) {
                int row = m0 + wr * 64 + m * 16 + g * 4 + j;
                int col = n0 + wc * 128 + n * 16 + r16;
                float v = acc[m][n][j];
                if (sig) v = 1.f / (1.f + expf(-v));
                O[(size_t)row * N + col] = f2b(v);
            }
}

// ------------------------------------------------ WKV segmented scan
__global__ void wkv_p1(const float* __restrict__ td, const u16* __restrict__ K,
                       const u16* __restrict__ V, float* __restrict__ st) {
    int bc = blockIdx.x * 256 + threadIdx.x;
    int seg = blockIdx.y;
    int b = bc / C_, c = bc - b * C_;
    float w = -expf(td[c]);
    size_t off = (size_t)b * T_ * C_ + (size_t)seg * WSEG * C_ + c;
    float aa = 0.f, bb = 0.f, pp = -1e38f;
#pragma unroll 4
    for (int i = 0; i < WSEG; ++i) {
        float kt = b2f(K[off + (size_t)i * C_]);
        float vt = b2f(V[off + (size_t)i * C_]);
        float ww2 = pp + w;
        float p2 = fmaxf(ww2, kt);
        float e1 = expf(ww2 - p2);
        float e2 = expf(kt - p2);
        aa = e1 * aa + e2 * vt;
        bb = e1 * bb + e2;
        pp = p2;
    }
    int sidx = seg * 3 * BC_ + bc;
    st[sidx] = aa; st[sidx + BC_] = bb; st[sidx + 2 * BC_] = pp;
}

__global__ void wkv_p2(const float* __restrict__ td, const float* __restrict__ st,
                       float* __restrict__ ini) {
    int bc = blockIdx.x * 256 + threadIdx.x;
    int c = bc % C_;
    float wL = -expf(td[c]) * (float)WSEG;
    float aa = 0.f, bb = 0.f, pp = -1e38f;
    for (int s = 0; s < NWSEG; ++s) {
        int sidx = s * 3 * BC_ + bc;
        ini[sidx] = aa; ini[sidx + BC_] = bb; ini[sidx + 2 * BC_] = pp;
        float la = st[sidx], lb = st[sidx + BC_], lp = st[sidx + 2 * BC_];
        float ppw = pp + wL;
        float p = fmaxf(ppw, lp);
        float e1 = expf(ppw - p), e2 = expf(lp - p);
        aa = e1 * aa + e2 * la;
        bb = e1 * bb + e2 * lb;
        pp = p;
    }
}

// p3 applies the sigmoid(R) gate: writes RY = R * y
__global__ void wkv_p3(const float* __restrict__ td, const float* __restrict__ tf,
                       const u16* __restrict__ K, const u16* __restrict__ V,
                       const u16* __restrict__ R, const float* __restrict__ ini,
                       u16* __restrict__ RY) {
    int bc = blockIdx.x * 256 + threadIdx.x;
    int seg = blockIdx.y;
    int b = bc / C_, c = bc - b * C_;
    float w = -expf(td[c]);
    float u = tf[c];
    int sidx = seg * 3 * BC_ + bc;
    float aa = ini[sidx], bb = ini[sidx + BC_], pp = ini[sidx + 2 * BC_];
    size_t off = (size_t)b * T_ * C_ + (size_t)seg * WSEG * C_ + c;
#pragma unroll 4
    for (int i = 0; i < WSEG; ++i) {
        float kt = b2f(K[off + (size_t)i * C_]);
        float vt = b2f(V[off + (size_t)i * C_]);
        float rr = b2f(R[off + (size_t)i * C_]);
        float ww = u + kt;
        float p = fmaxf(pp, ww);
        float e1 = expf(pp - p);
        float e2 = expf(ww - p);
        RY[off + (size_t)i * C_] = f2b(rr * (e1 * aa + e2 * vt) / (e1 * bb + e2));
        float ww2 = pp + w;
        float p2 = fmaxf(ww2, kt);
        float e1b = expf(ww2 - p2);
        float e2b = expf(kt - p2);
        aa = e1b * aa + e2b * vt;
        bb = e1b * bb + e2b;
        pp = p2;
    }
}

// ------------------------------------------------ LIF + residual (bf16 input, segmented warm-up)
__global__ void lif_add_b(const u16* __restrict__ cur, const float* __restrict__ base,
                          float* __restrict__ out) {
    int bc = blockIdx.x * 256 + threadIdx.x;
    int seg = blockIdx.y;
    int b = bc / C_, c = bc - b * C_;
    size_t rowbase = (size_t)b * T_ * C_ + c;
    int t0 = seg * LSEG;
    int tw = t0 - LWARM; if (tw < 0) tw = 0;
    int nw = t0 - tw;
    float v = 0.f;
    const u16* cp = cur + rowbase + (size_t)tw * C_;
#pragma unroll 8
    for (int i = 0; i < nw; ++i) {
        float xt = b2f(cp[(size_t)i * C_]);
        v += (xt - v) * 0.5f;
        v = (v >= 1.f) ? 0.f : v;
    }
    const u16* c2 = cur + rowbase + (size_t)t0 * C_;
    const float* bp = base + rowbase + (size_t)t0 * C_;
    float* op = out + rowbase + (size_t)t0 * C_;
#pragma unroll 8
    for (int i = 0; i < LSEG; ++i) {
        float xt = b2f(c2[(size_t)i * C_]);
        v += (xt - v) * 0.5f;
        float sp = (v >= 1.f) ? 1.f : 0.f;
        op[(size_t)i * C_] = bp[(size_t)i * C_] + sp;
        v = (sp > 0.f) ? 0.f : v;
    }
}

// ------------------------------------------------ launcher
extern "C" void kernel_launch(void* const* d_in, const int* in_sizes, int n_in,
                              void* d_out, int out_size, void* d_ws, size_t ws_size,
                              hipStream_t stream) {
    const float* x    = (const float*)d_in[0];
    const float* ln1w = (const float*)d_in[1];
    const float* ln1b = (const float*)d_in[2];
    const float* ln2w = (const float*)d_in[3];
    const float* ln2b = (const float*)d_in[4];
    const float* td   = (const float*)d_in[5];
    const float* tf   = (const float*)d_in[6];
    const float* amk  = (const float*)d_in[7];
    const float* amv  = (const float*)d_in[8];
    const float* amr  = (const float*)d_in[9];
    const float* aWk  = (const float*)d_in[10];
    const float* aWv  = (const float*)d_in[11];
    const float* aWr  = (const float*)d_in[12];
    const float* aWo  = (const float*)d_in[13];
    const float* fmk  = (const float*)d_in[14];
    const float* fmr  = (const float*)d_in[15];
    const float* fWk  = (const float*)d_in[16];
    const float* fWv  = (const float*)d_in[17];
    const float* fWr  = (const float*)d_in[18];
    float* out = (float*)d_out;

    const size_t NBC = (size_t)BT_ * C_;
    u16* WkT = (u16*)d_ws;
    u16* WvT = WkT + 589824;
    u16* WrT = WvT + 589824;
    u16* WoT = WrT + 589824;
    u16* FrT = WoT + 589824;
    u16* FkT = FrT + 589824;                  // [3072][768]
    u16* FvT = FkT + 2359296;                 // [768][3072]
    float* st  = (float*)(FvT + 2359296);
    float* ini = st + NWSEG * 3 * BC_;
    u16* S0 = (u16*)(ini + NWSEG * 3 * BC_);
    u16* S1 = S0 + NBC;
    u16* S2 = S1 + NBC;
    u16* S3 = S2 + NBC;
    u16* Hbuf = S3 + NBC;
    size_t fixed_b = (size_t)((char*)Hbuf - (char*)d_ws);

    // FFN chunking (H bf16 chunk + F bf16 chunk after it)
    int NCH = 4;
    if (ws_size >= fixed_b + ((size_t)BT_ * H_ + NBC) * 2) NCH = 1;
    else if (ws_size >= fixed_b + ((size_t)(BT_ / 2) * H_ + NBC / 2) * 2) NCH = 2;
    const int CH = BT_ / NCH;
    u16* Fbuf = Hbuf + (size_t)CH * H_;

    u16* Kb = (u16*)d_out;
    u16* Vb = Kb + NBC;

    // 0. weights -> bf16 [N][K] (one batched dispatch)
    {
        TC7 jobs;
        const float* srcs[7] = {aWk, aWv, aWr, aWo, fWr, fWk, fWv};
        u16* dsts[7] = {WkT, WvT, WrT, WoT, FrT, FkT, FvT};
        int Rs[7]    = {768, 768, 768, 768, 768, 768, 3072};
        int Ns[7]    = {768, 768, 768, 768, 768, 3072, 768};
        int b0 = 0;
        for (int k = 0; k < 7; ++k) {
            jobs.j[k].s = srcs[k]; jobs.j[k].d = dsts[k];
            jobs.j[k].R = Rs[k]; jobs.j[k].Ncol = Ns[k];
            jobs.j[k].nbx = Ns[k] / 32; jobs.j[k].b0 = b0;
            b0 += (Ns[k] / 32) * (Rs[k] / 32);
        }
        tcast_all<<<b0, 256, 0, stream>>>(jobs);
    }

    // 1. xk,xv,xr = mix(ln1(x)) -> S0,S1,S2
    lnmix<3><<<BT_, 256, 0, stream>>>(x, ln1w, ln1b, amk, amv, amr, S0, S1, S2);
    // 2. K,V,sigmoid(R) in one fused dispatch
    {
        P3 p{S0, S1, S2, WkT, WvT, WrT, Kb, Vb, S3};
        proj3<<<dim3(3, 128, 3), 256, 0, stream>>>(p, C_, C_);
    }
    // 3. RY = sigmoid(R) * wkv(K,V) -> S0
    wkv_p1<<<dim3(BC_ / 256, NWSEG), 256, 0, stream>>>(td, Kb, Vb, st);
    wkv_p2<<<BC_ / 256, 256, 0, stream>>>(td, st, ini);
    wkv_p3<<<dim3(BC_ / 256, NWSEG), 256, 0, stream>>>(td, tf, Kb, Vb, S3, ini, S0);
    // 4. A_out = RY @ Wo -> bf16 S1
    gemm2<0, false><<<dim3(3, 128), 256, 0, stream>>>(S0, WoT, S1, nullptr, C_, C_);
    // 5. X2 = x + lif(A_out) -> d_out
    lif_add_b<<<dim3(BC_ / 256, NLSEG), 256, 0, stream>>>(S1, x, out);
    // 6. xk2 -> S0, xr2 -> S1
    lnmix<2><<<BT_, 256, 0, stream>>>(out, ln2w, ln2b, fmk, fmr, nullptr, S0, S1, nullptr);
    // 7. RR = sigmoid(xr2 @ fWr) -> S2
    gemm2<1, false><<<dim3(3, 128), 256, 0, stream>>>(S1, FrT, S2, nullptr, C_, C_);
    // 8. FFN per chunk: H = relu^2(xk2 @ fWk); F = RR * (H @ fWv) bf16; out += lif(F)
    for (int ch = 0; ch < NCH; ++ch) {
        const u16* xk2c = S0 + (size_t)ch * CH * C_;
        const u16* rrc  = S2 + (size_t)ch * CH * C_;
        gemm2<2, false><<<dim3(12, CH / 128), 256, 0, stream>>>(xk2c, FkT, Hbuf, nullptr, H_, C_);
        gemm2<0, true><<<dim3(3, CH / 128), 256, 0, stream>>>(Hbuf, FvT, Fbuf, rrc, C_, H_);
        lif_add_b<<<dim3((CH / T_) * C_ / 256, NLSEG), 256, 0, stream>>>(
            Fbuf, out + (size_t)ch * CH * C_, out + (size_t)ch * CH * C_);
    }
}